// Round 9
// baseline (745.541 us; speedup 1.0000x reference)
//
#include <hip/hip_runtime.h>
#include <hip/hip_bf16.h>
#include <math.h>

#define N_NODES 20000
#define N_EDGES 160000
#define T_STEPS 8
#define F_INC   256
#define HEADS   4
#define CCH     128
#define KC      512   // HEADS*CCH
#define GHD     128
#define G3      384
#define SLOPE   0.2f
#define SEG     (N_EDGES + N_NODES)   // edges + self loops per t
#define TN      (T_STEPS * N_NODES)   // 160000
#define SCAN_BLKS ((TN + 1023) / 1024)  // 157

typedef unsigned short u16;
typedef __attribute__((ext_vector_type(8))) short bf16x8;
typedef __attribute__((ext_vector_type(4))) float f32x4;

__device__ __forceinline__ float leakyf(float x) { return x > 0.f ? x : SLOPE * x; }
__device__ __forceinline__ float b2f(u16 u) {
  union { unsigned int i; float f; } x; x.i = ((unsigned int)u) << 16; return x.f;
}
__device__ __forceinline__ u16 f2b(float f) {
  union { float f; unsigned int i; } u; u.f = f;
  unsigned int r = u.i + 0x7FFFu + ((u.i >> 16) & 1u);
  return (u16)(r >> 16);
}
__device__ __forceinline__ float sigf(float x) { return 1.f / (1.f + expf(-x)); }

// async global->LDS 16B (wave-uniform LDS base + lane*16; per-lane global src)
__device__ __forceinline__ void gload16(const void* g, void* l) {
  __builtin_amdgcn_global_load_lds(
      (const __attribute__((address_space(1))) unsigned int*)g,
      (__attribute__((address_space(3))) unsigned int*)l, 16, 0, 0);
}

// pack 8 f32 -> bf16x8 via v_cvt_pk_bf16_f32 (no builtin on gfx950)
__device__ __forceinline__ bf16x8 cvt8(f32x4 lo, f32x4 hi) {
  union { unsigned int u[4]; bf16x8 v; } r;
  asm("v_cvt_pk_bf16_f32 %0, %1, %2" : "=v"(r.u[0]) : "v"(lo[0]), "v"(lo[1]));
  asm("v_cvt_pk_bf16_f32 %0, %1, %2" : "=v"(r.u[1]) : "v"(lo[2]), "v"(lo[3]));
  asm("v_cvt_pk_bf16_f32 %0, %1, %2" : "=v"(r.u[2]) : "v"(hi[0]), "v"(hi[1]));
  asm("v_cvt_pk_bf16_f32 %0, %1, %2" : "=v"(r.u[3]) : "v"(hi[2]), "v"(hi[3]));
  return r.v;
}

// ---------------------------------------------------------------------------
// bf16 MFMA GEMM: C[M,Nt] = A[M,K] @ B^T (+bias). B (Nt,K) bf16.
// AFP32=1: A fp32, converted at fragment-read (v_cvt_pk_bf16_f32).
// FUSE=1: fused a_src/a_dst row-dots (xw gemm).
// FUSE=2: fused classifier: o=leaky(tanh(C)), logits=o@W_cls^T + b_cls,
//         log_softmax -> out (no C write). attS/attD = W_cls rows,
//         bias = b_cls, asrc = out.
// ---------------------------------------------------------------------------
template <int OBF, int FUSE, int AFP32>
__global__ __launch_bounds__(256) void gemm_bf16(
    const void* __restrict__ Ain, const u16* __restrict__ B,
    const float* __restrict__ bias, void* __restrict__ Cout,
    int M, int K, int Nt, int swz,
    const float* __restrict__ attS, const float* __restrict__ attD,
    float* __restrict__ asrc, float* __restrict__ adst)
{
  __shared__ __align__(16) char AsRaw[128 * 32 * 4];
  __shared__ u16 Bs[128][32];
  __shared__ float s_as[128], s_ad[128];
  float* AsF = (float*)AsRaw;
  u16 (*Asb)[32] = (u16(*)[32])AsRaw;
  const int tid  = threadIdx.x;
  const int wave = tid >> 6, lane = tid & 63;
  const int wr = (wave >> 1) * 64, wc = (wave & 1) * 64;
  int bx = blockIdx.x, by = blockIdx.y;
  if (swz) {
    const int gx = gridDim.x;
    const int nwg = gx * (int)gridDim.y;
    const int lin = by * gx + bx;
    const int q = nwg >> 3, r = nwg & 7;
    const int xcd = lin & 7, idx = lin >> 3;
    const int wg = (xcd < r ? xcd * (q + 1) : r * (q + 1) + (xcd - r) * q) + idx;
    bx = wg % gx; by = wg / gx;
  }
  const int bm = by * 128, bn = bx * 128;
  const int l15 = lane & 15, g = lane >> 4;

  if (FUSE && tid < 128) { s_as[tid] = 0.f; s_ad[tid] = 0.f; }

  const int sr = tid >> 2, sd = tid & 3;
  const int ss = sd ^ ((sr >> 1) & 3);
  const u16* aS0 = 0; const u16* aS1 = 0; u16* lA0 = 0; u16* lA1 = 0;
  const float* aF[4]; float* lAF[4];
  if (AFP32) {
    const float* Af = (const float*)Ain;
    const int row0 = tid >> 3, sd8 = tid & 7;
    const int ss8 = sd8 ^ (row0 & 7);
    #pragma unroll
    for (int p = 0; p < 4; ++p) {
      int row = row0 + p * 32;
      aF[p] = Af + (size_t)min(bm + row, M - 1) * K + ss8 * 4;
      lAF[p] = AsF + (size_t)(p * 256 + (tid & ~63)) * 4;
    }
  } else {
    const u16* Ab = (const u16*)Ain;
    aS0 = Ab + (size_t)min(bm + sr,      M - 1) * K + ss * 8;
    aS1 = Ab + (size_t)min(bm + 64 + sr, M - 1) * K + ss * 8;
    lA0 = (u16*)AsRaw + (size_t)(tid & ~63) * 8;
    lA1 = lA0 + 2048;
  }
  const u16* bS0 = B + (size_t)(bn + sr)      * K + ss * 8;
  const u16* bS1 = B + (size_t)(bn + 64 + sr) * K + ss * 8;
  u16* lB0 = &Bs[0][0] + (size_t)(tid & ~63) * 8;
  u16* lB1 = lB0 + 2048;

  f32x4 acc[4][4];
  #pragma unroll
  for (int m = 0; m < 4; ++m)
    #pragma unroll
    for (int n = 0; n < 4; ++n)
      #pragma unroll
      for (int j = 0; j < 4; ++j) acc[m][n][j] = 0.f;

  const int nK = K >> 5;
  for (int kt = 0; kt < nK; ++kt) {
    const int ko = kt * 32;
    if (AFP32) {
      #pragma unroll
      for (int p = 0; p < 4; ++p) gload16(aF[p] + ko, lAF[p]);
    } else {
      gload16(aS0 + ko, lA0);
      gload16(aS1 + ko, lA1);
    }
    gload16(bS0 + ko, lB0);
    gload16(bS1 + ko, lB1);
    __syncthreads();
    bf16x8 af[4], bfr[4];
    #pragma unroll
    for (int m = 0; m < 4; ++m) {
      int row = wr + m * 16 + l15;
      if (AFP32) {
        int s0 = (2 * g) ^ (row & 7), s1 = (2 * g + 1) ^ (row & 7);
        f32x4 lo = *(const f32x4*)&AsF[row * 32 + s0 * 4];
        f32x4 hi = *(const f32x4*)&AsF[row * 32 + s1 * 4];
        af[m] = cvt8(lo, hi);
      } else {
        af[m] = *(const bf16x8*)&Asb[row][(g ^ ((row >> 1) & 3)) * 8];
      }
      int rowb = wc + m * 16 + l15;
      bfr[m] = *(const bf16x8*)&Bs[rowb][(g ^ ((rowb >> 1) & 3)) * 8];
    }
    #pragma unroll
    for (int m = 0; m < 4; ++m)
      #pragma unroll
      for (int n = 0; n < 4; ++n)
        acc[m][n] = __builtin_amdgcn_mfma_f32_16x16x32_bf16(af[m], bfr[n], acc[m][n], 0, 0, 0);
    __syncthreads();
  }
  if (FUSE != 2) {
    #pragma unroll
    for (int m = 0; m < 4; ++m) {
      int row0 = bm + wr + m * 16 + g * 4;
      #pragma unroll
      for (int n = 0; n < 4; ++n) {
        int col = bn + wc + n * 16 + l15;
        float bv = bias ? bias[col] : 0.f;
        #pragma unroll
        for (int j = 0; j < 4; ++j) {
          int row = row0 + j;
          if (row < M) {
            float v = acc[m][n][j] + bv;
            if (OBF) ((u16*)Cout)[(size_t)row * Nt + col] = f2b(v);
            else     ((float*)Cout)[(size_t)row * Nt + col] = v;
          }
        }
      }
    }
  }
  if (FUSE) {
    float ps[4][4], pd[4][4];
    #pragma unroll
    for (int m = 0; m < 4; ++m)
      #pragma unroll
      for (int j = 0; j < 4; ++j) { ps[m][j] = 0.f; pd[m][j] = 0.f; }
    #pragma unroll
    for (int n = 0; n < 4; ++n) {
      int cl = wc + n * 16 + l15;
      float wsv = attS[bn + cl], wdv = attD[bn + cl];
      #pragma unroll
      for (int m = 0; m < 4; ++m)
        #pragma unroll
        for (int j = 0; j < 4; ++j) {
          float av = acc[m][n][j];
          if (FUSE == 2) av = leakyf(tanhf(av));
          ps[m][j] = fmaf(av, wsv, ps[m][j]);
          pd[m][j] = fmaf(av, wdv, pd[m][j]);
        }
    }
    #pragma unroll
    for (int m = 0; m < 4; ++m)
      #pragma unroll
      for (int j = 0; j < 4; ++j)
        #pragma unroll
        for (int msk = 8; msk >= 1; msk >>= 1) {
          ps[m][j] += __shfl_xor(ps[m][j], msk);
          pd[m][j] += __shfl_xor(pd[m][j], msk);
        }
    if (l15 == 0) {
      #pragma unroll
      for (int m = 0; m < 4; ++m)
        #pragma unroll
        for (int j = 0; j < 4; ++j) {
          atomicAdd(&s_as[wr + m * 16 + g * 4 + j], ps[m][j]);
          atomicAdd(&s_ad[wr + m * 16 + g * 4 + j], pd[m][j]);
        }
    }
    __syncthreads();
    if (tid < 128) {
      int row = bm + tid;
      if (row < M) {
        if (FUSE == 1) {
          int h = bn >> 7;
          asrc[(size_t)row * 4 + h] = s_as[tid];
          adst[(size_t)row * 4 + h] = s_ad[tid];
        } else {
          float l0 = s_as[tid] + bias[0];
          float l1 = s_ad[tid] + bias[1];
          float mx = fmaxf(l0, l1);
          float lse = mx + logf(expf(l0 - mx) + expf(l1 - mx));
          asrc[(size_t)row * 2 + 0] = l0 - lse;
          asrc[(size_t)row * 2 + 1] = l1 - lse;
        }
      }
    }
  }
}

// ---------------------------------------------------------------------------
// merged small-weight converts: W_ih, W_hh, W_att_in, W_att_out (8 elems/thr)
// ---------------------------------------------------------------------------
__global__ void convert_weights(const float* __restrict__ w_ih, const float* __restrict__ w_hh,
                                const float* __restrict__ w_in, const float* __restrict__ w_out,
                                u16* __restrict__ wihb, u16* __restrict__ whhb,
                                u16* __restrict__ winb, u16* __restrict__ woutb)
{
  int i = blockIdx.x * 256 + threadIdx.x;   // 18432 threads
  const float* src; u16* dst; int base;
  if      (i < 6144)  { src = w_ih;  dst = wihb;  base = i; }
  else if (i < 12288) { src = w_hh;  dst = whhb;  base = i - 6144; }
  else if (i < 14336) { src = w_in;  dst = winb;  base = i - 12288; }
  else                { src = w_out; dst = woutb; base = i - 14336; }
  int o = base * 8;
  float4 v0 = *(const float4*)(src + o);
  float4 v1 = *(const float4*)(src + o + 4);
  bf16x8 ov;
  ov[0] = (short)f2b(v0.x); ov[1] = (short)f2b(v0.y);
  ov[2] = (short)f2b(v0.z); ov[3] = (short)f2b(v0.w);
  ov[4] = (short)f2b(v1.x); ov[5] = (short)f2b(v1.y);
  ov[6] = (short)f2b(v1.z); ov[7] = (short)f2b(v1.w);
  *(bf16x8*)(dst + o) = ov;
}

__global__ void conv_transpose_wgat(const float* __restrict__ src, u16* __restrict__ dst) {
  int idx = blockIdx.x * 256 + threadIdx.x;
  if (idx >= KC * F_INC) return;
  int n = idx >> 8, k = idx & 255;
  dst[(size_t)n * F_INC + k] = f2b(src[(size_t)k * KC + n]);
}

// ---------------------------------------------------------------------------
// Batched edge counting-sort (all T at once). offs is a FLAT global scan of
// (counts+1) over all T*N nodes; per-t bases (t*SEG) emerge automatically.
// ---------------------------------------------------------------------------
__global__ void count_kernel(const int* __restrict__ graph, int* __restrict__ counts) {
  int e = blockIdx.x * 256 + threadIdx.x;
  int t = blockIdx.y;
  if (e < N_EDGES) {
    int d = graph[(size_t)t * 2 * N_EDGES + N_EDGES + e];
    atomicAdd(&counts[t * N_NODES + d], 1);
  }
}

__global__ __launch_bounds__(1024) void scanA(
    const int* __restrict__ counts, int* __restrict__ offs, int* __restrict__ bsums)
{
  const int tid = threadIdx.x, lane = tid & 63, w = tid >> 6;
  __shared__ int s_wt[16];
  int i = blockIdx.x * 1024 + tid;
  int v = (i < TN) ? (counts[i] + 1) : 0;   // +1 self loop
  int x = v;
  #pragma unroll
  for (int d = 1; d < 64; d <<= 1) {
    int nvl = __shfl_up(x, d, 64);
    if (lane >= d) x += nvl;
  }
  if (lane == 63) s_wt[w] = x;
  __syncthreads();
  if (tid < 16) {
    int y = s_wt[tid];
    #pragma unroll
    for (int d = 1; d < 16; d <<= 1) {
      int nvl = __shfl_up(y, d, 64);
      if (tid >= d) y += nvl;
    }
    s_wt[tid] = y;
  }
  __syncthreads();
  int wbase = (w > 0) ? s_wt[w - 1] : 0;
  if (i < TN) offs[i] = wbase + x - v;       // block-local exclusive
  if (tid == 1023) bsums[blockIdx.x] = s_wt[15];
}

__global__ void scanB(int* __restrict__ bsums, int* __restrict__ offs) {
  const int lane = threadIdx.x;  // 64 threads, 1 block
  int carry = 0;
  for (int base = 0; base < 192; base += 64) {
    int idx = base + lane;
    int v = (idx < SCAN_BLKS) ? bsums[idx] : 0;
    int x = v;
    #pragma unroll
    for (int d = 1; d < 64; d <<= 1) {
      int nvl = __shfl_up(x, d, 64);
      if (lane >= d) x += nvl;
    }
    if (idx < SCAN_BLKS) bsums[idx] = carry + x - v;   // exclusive
    carry += __shfl(x, 63);
  }
  if (lane == 0) offs[TN] = carry;   // == T_STEPS * SEG
}

__global__ __launch_bounds__(1024) void scanC(int* __restrict__ offs, const int* __restrict__ bsums) {
  int i = blockIdx.x * 1024 + threadIdx.x;
  if (i < TN) offs[i] += bsums[blockIdx.x];
}

__global__ void scatter_kernel(const int* __restrict__ graph, const int* __restrict__ offs,
                               int* __restrict__ cursor, int* __restrict__ ssrc)
{
  int i = blockIdx.x * 256 + threadIdx.x;
  int t = blockIdx.y;
  if (i >= SEG) return;
  int s, d;
  if (i < N_EDGES) {
    s = graph[(size_t)t * 2 * N_EDGES + i];
    d = graph[(size_t)t * 2 * N_EDGES + N_EDGES + i];
  } else {
    s = d = i - N_EDGES;
  }
  int pos = offs[t * N_NODES + d] + atomicAdd(&cursor[t * N_NODES + d], 1);
  ssrc[pos] = s;
}

// ---------------------------------------------------------------------------
// Batched aggregate (structure proven in round 7; flat offs indexing).
// ---------------------------------------------------------------------------
__global__ __launch_bounds__(256) void aggregate_kernel(
    const u16* __restrict__ xw, const float* __restrict__ a_src,
    const float* __restrict__ a_dst, const float* __restrict__ b_gat,
    const int* __restrict__ offs, const int* __restrict__ ssrc,
    u16* __restrict__ yout)
{
  const int wv = threadIdx.x >> 6, lane = threadIdx.x & 63;
  const int nd = blockIdx.x * 4 + wv;
  const int t  = blockIdx.y;
  const int ob = t * N_NODES + nd;
  const int beg = offs[ob], end = offs[ob + 1];
  const size_t rowbase = (size_t)t * N_NODES;
  const int he   = lane & 3;
  const int eidx = lane >> 2;
  const int hl   = lane >> 4;
  const float advh = a_dst[(rowbase + nd) * 4 + he];

  float m = -INFINITY, ssum = 0.f;
  float acc[8] = {0.f,0.f,0.f,0.f,0.f,0.f,0.f,0.f};

#define FMA8(W, X)                                                        \
    { float _w = (W);                                                     \
      acc[0] = fmaf(_w, __uint_as_float((unsigned)(X).x << 16), acc[0]);  \
      acc[1] = fmaf(_w, __uint_as_float((unsigned)(X).x & 0xffff0000u), acc[1]); \
      acc[2] = fmaf(_w, __uint_as_float((unsigned)(X).y << 16), acc[2]);  \
      acc[3] = fmaf(_w, __uint_as_float((unsigned)(X).y & 0xffff0000u), acc[3]); \
      acc[4] = fmaf(_w, __uint_as_float((unsigned)(X).z << 16), acc[4]);  \
      acc[5] = fmaf(_w, __uint_as_float((unsigned)(X).z & 0xffff0000u), acc[5]); \
      acc[6] = fmaf(_w, __uint_as_float((unsigned)(X).w << 16), acc[6]);  \
      acc[7] = fmaf(_w, __uint_as_float((unsigned)(X).w & 0xffff0000u), acc[7]); }
#define LDE(SVAR) (*(const int4*)&xw[(rowbase + (SVAR)) * KC + lane * 8])

  for (int base = beg; base < end; base += 16) {
    const int cnt = min(16, end - base);
    const int e = base + eidx;
    const int sidx = (e < end) ? ssrc[e] : ssrc[base];
    const float av = a_src[(rowbase + sidx) * 4 + he];
    const float a = (eidx < cnt) ? leakyf(av + advh) : -INFINITY;
    float cm = a;
    cm = fmaxf(cm, __shfl_xor(cm, 4));
    cm = fmaxf(cm, __shfl_xor(cm, 8));
    cm = fmaxf(cm, __shfl_xor(cm, 16));
    cm = fmaxf(cm, __shfl_xor(cm, 32));
    const float nm = fmaxf(m, cm);
    const float sc = expf(m - nm);
    const float w = expf(a - nm);
    float ts = w;
    ts += __shfl_xor(ts, 4);
    ts += __shfl_xor(ts, 8);
    ts += __shfl_xor(ts, 16);
    ts += __shfl_xor(ts, 32);
    ssum = ssum * sc + ts;
    m = nm;
    const float schl = __shfl(sc, hl);
    #pragma unroll
    for (int k = 0; k < 8; ++k) acc[k] *= schl;

    const int cpad = (cnt + 3) & ~3;
    int b4 = 0;
    for (; b4 + 8 <= cpad; b4 += 8) {
      const int s0 = __shfl(sidx, (b4 + 0) << 2);
      const int s1 = __shfl(sidx, (b4 + 1) << 2);
      const int s2 = __shfl(sidx, (b4 + 2) << 2);
      const int s3 = __shfl(sidx, (b4 + 3) << 2);
      const int s4 = __shfl(sidx, (b4 + 4) << 2);
      const int s5 = __shfl(sidx, (b4 + 5) << 2);
      const int s6 = __shfl(sidx, (b4 + 6) << 2);
      const int s7 = __shfl(sidx, (b4 + 7) << 2);
      const int4 x0 = LDE(s0); const int4 x1 = LDE(s1);
      const int4 x2 = LDE(s2); const int4 x3 = LDE(s3);
      const int4 x4 = LDE(s4); const int4 x5 = LDE(s5);
      const int4 x6 = LDE(s6); const int4 x7 = LDE(s7);
      const float w0 = __shfl(w, ((b4 + 0) << 2) + hl);
      const float w1 = __shfl(w, ((b4 + 1) << 2) + hl);
      const float w2 = __shfl(w, ((b4 + 2) << 2) + hl);
      const float w3 = __shfl(w, ((b4 + 3) << 2) + hl);
      const float w4 = __shfl(w, ((b4 + 4) << 2) + hl);
      const float w5 = __shfl(w, ((b4 + 5) << 2) + hl);
      const float w6 = __shfl(w, ((b4 + 6) << 2) + hl);
      const float w7 = __shfl(w, ((b4 + 7) << 2) + hl);
      FMA8(w0, x0); FMA8(w1, x1); FMA8(w2, x2); FMA8(w3, x3);
      FMA8(w4, x4); FMA8(w5, x5); FMA8(w6, x6); FMA8(w7, x7);
    }
    if (b4 < cpad) {
      const int s0 = __shfl(sidx, (b4 + 0) << 2);
      const int s1 = __shfl(sidx, (b4 + 1) << 2);
      const int s2 = __shfl(sidx, (b4 + 2) << 2);
      const int s3 = __shfl(sidx, (b4 + 3) << 2);
      const int4 x0 = LDE(s0); const int4 x1 = LDE(s1);
      const int4 x2 = LDE(s2); const int4 x3 = LDE(s3);
      const float w0 = __shfl(w, ((b4 + 0) << 2) + hl);
      const float w1 = __shfl(w, ((b4 + 1) << 2) + hl);
      const float w2 = __shfl(w, ((b4 + 2) << 2) + hl);
      const float w3 = __shfl(w, ((b4 + 3) << 2) + hl);
      FMA8(w0, x0); FMA8(w1, x1); FMA8(w2, x2); FMA8(w3, x3);
    }
  }
#undef LDE
#undef FMA8

  const float sh = __shfl(ssum, hl);
  const float inv = 1.f / (sh + 1e-16f);
  #pragma unroll
  for (int k = 0; k < 8; ++k) {
    acc[k] *= inv;
    acc[k] += __shfl_xor(acc[k], 16);
    acc[k] += __shfl_xor(acc[k], 32);
  }
  if (lane < 16) {
    bf16x8 ov;
    #pragma unroll
    for (int k = 0; k < 8; ++k) {
      float v = acc[k] * 0.25f + b_gat[lane * 8 + k];
      ov[k] = (short)f2b(leakyf(v));
    }
    *(bf16x8*)&yout[(rowbase + nd) * GHD + lane * 8] = ov;
  }
}

// ---------------------------------------------------------------------------
// Fully-fused GRU: ONE kernel, 625 blocks x 32 rows, 8 steps. Per step BOTH
// gemms (gi = y@W_ih^T, gh = h@W_hh^T) via MFMA; h carried fp32 in registers
// and bf16 in swizzled LDS (hA) feeding the next step's A-fragments; y staged
// per-t into yA; W slices per-kt via global_load_lds (L2-hot); gh/gi restaged
// through LDS for the combine. hA=0 initially makes t=0 uniform (gh=b_hh).
// ---------------------------------------------------------------------------
__global__ __launch_bounds__(256) void gru_seq(
    const u16* __restrict__ Whh, const u16* __restrict__ Wih,
    const float* __restrict__ b_hh, const float* __restrict__ b_ih,
    const u16* __restrict__ yall, u16* __restrict__ ctx)
{
  __shared__ u16 hA[32 * 128];     // 8 KB  h bf16, slot^=(row&7) swizzle
  __shared__ u16 yA[32 * 128];     // 8 KB  y bf16, same swizzle
  __shared__ u16 w1[384 * 32];     // 24 KB Whh kt-slice -> gh
  __shared__ u16 w2[384 * 32];     // 24 KB Wih kt-slice -> gi
  const int tid = threadIdx.x, lane = tid & 63, wv = tid >> 6;
  const int l15 = lane & 15, g = lane >> 4;
  const int bm = blockIdx.x * 32;   // 625*32 = 20000 exact

  // W staging pointers (proven scheme from gru_fused)
  const int sr = tid >> 2, sd = tid & 3;
  const int ssb = sd ^ ((sr >> 1) & 3);
  const u16* hS[6]; const u16* iS[6]; u16* l1p[6]; u16* l2p[6];
  #pragma unroll
  for (int p = 0; p < 6; ++p) {
    hS[p] = Whh + (size_t)(sr + p * 64) * GHD + ssb * 8;
    iS[p] = Wih + (size_t)(sr + p * 64) * GHD + ssb * 8;
    l1p[p] = w1 + (size_t)(p * 256 + (tid & ~63)) * 8;
    l2p[p] = w2 + (size_t)(p * 256 + (tid & ~63)) * 8;
  }
  // yA staging geometry: idx = tid + p*256; row=idx>>4; slot=idx&15
  const int yr0 = tid >> 4,        ys0 = tid & 15, gs0 = ys0 ^ (yr0 & 7);
  const int yr1 = (tid + 256) >> 4, gs1 = (tid & 15) ^ (yr1 & 7);
  u16* yd0 = yA + (size_t)(tid & ~63) * 8;
  u16* yd1 = yA + (size_t)(256 + (tid & ~63)) * 8;
  // hoisted biases (channel c = wv*96 + n*16 + l15)
  float bbh[6], bbi[6];
  #pragma unroll
  for (int n = 0; n < 6; ++n) {
    bbh[n] = b_hh[wv * 96 + n * 16 + l15];
    bbi[n] = b_ih[wv * 96 + n * 16 + l15];
  }
  // combine mapping
  const int cr = tid >> 3, cg = (tid & 7) * 8;
  const size_t cb = (size_t)(bm + cr) * GHD;
  float hp[2][8];
  #pragma unroll
  for (int q = 0; q < 2; ++q)
    #pragma unroll
    for (int k = 0; k < 8; ++k) hp[q][k] = 0.f;

  { // zero hA (h0 = 0)
    bf16x8 z8 = {0,0,0,0,0,0,0,0};
    *(bf16x8*)&hA[tid * 16] = z8;
    *(bf16x8*)&hA[tid * 16 + 8] = z8;
  }
  __syncthreads();

  for (int t = 0; t < T_STEPS; ++t) {
    const u16* ysrc = yall + ((size_t)t * N_NODES + bm) * GHD;
    gload16(ysrc + (size_t)yr0 * GHD + gs0 * 8, yd0);
    gload16(ysrc + (size_t)yr1 * GHD + gs1 * 8, yd1);
    f32x4 accG[2][6], accI[2][6];
    #pragma unroll
    for (int m = 0; m < 2; ++m)
      #pragma unroll
      for (int n = 0; n < 6; ++n)
        #pragma unroll
        for (int j = 0; j < 4; ++j) { accG[m][n][j] = 0.f; accI[m][n][j] = 0.f; }

    #pragma unroll
    for (int kt = 0; kt < 4; ++kt) {
      const int ko = kt * 32;
      #pragma unroll
      for (int p = 0; p < 6; ++p) { gload16(hS[p] + ko, l1p[p]); gload16(iS[p] + ko, l2p[p]); }
      __syncthreads();
      bf16x8 afh[2], afy[2], bh[6], bi[6];
      #pragma unroll
      for (int m = 0; m < 2; ++m) {
        int row = m * 16 + l15;
        int sl = (kt * 4 + g) ^ (row & 7);
        afh[m] = *(const bf16x8*)&hA[row * 128 + sl * 8];
        afy[m] = *(const bf16x8*)&yA[row * 128 + sl * 8];
      }
      #pragma unroll
      for (int n = 0; n < 6; ++n) {
        int rowb = wv * 96 + n * 16 + l15;
        int slb = g ^ ((rowb >> 1) & 3);
        bh[n] = *(const bf16x8*)&w1[rowb * 32 + slb * 8];
        bi[n] = *(const bf16x8*)&w2[rowb * 32 + slb * 8];
      }
      #pragma unroll
      for (int m = 0; m < 2; ++m)
        #pragma unroll
        for (int n = 0; n < 6; ++n) {
          accG[m][n] = __builtin_amdgcn_mfma_f32_16x16x32_bf16(afh[m], bh[n], accG[m][n], 0, 0, 0);
          accI[m][n] = __builtin_amdgcn_mfma_f32_16x16x32_bf16(afy[m], bi[n], accI[m][n], 0, 0, 0);
        }
      __syncthreads();
    }
    // restage gh (+b_hh) -> w1, gi (+b_ih) -> w2 (swizzled row layout)
    #pragma unroll
    for (int m = 0; m < 2; ++m)
      #pragma unroll
      for (int n = 0; n < 6; ++n) {
        int c = wv * 96 + n * 16 + l15;
        #pragma unroll
        for (int j = 0; j < 4; ++j) {
          int r = m * 16 + g * 4 + j;
          int o = r * 384 + (((c >> 3) ^ (r & 7)) << 3) + (c & 7);
          w1[o] = f2b(accG[m][n][j] + bbh[n]);
          w2[o] = f2b(accI[m][n][j] + bbi[n]);
        }
      }
    __syncthreads();
    // combine
    u16* ctx_t = ctx + (size_t)t * N_NODES * GHD;
    #pragma unroll
    for (int q = 0; q < 2; ++q) {
      const int c0 = cg + q * 64;
      const int sl0 = ((c0 >> 3) ^ (cr & 7));
      const int sl1 = (((128 + c0) >> 3) ^ (cr & 7));
      const int sl2 = (((256 + c0) >> 3) ^ (cr & 7));
      bf16x8 hr8 = *(bf16x8*)&w1[cr * 384 + sl0 * 8];
      bf16x8 hz8 = *(bf16x8*)&w1[cr * 384 + sl1 * 8];
      bf16x8 hn8 = *(bf16x8*)&w1[cr * 384 + sl2 * 8];
      bf16x8 ir8 = *(bf16x8*)&w2[cr * 384 + sl0 * 8];
      bf16x8 iz8 = *(bf16x8*)&w2[cr * 384 + sl1 * 8];
      bf16x8 in8 = *(bf16x8*)&w2[cr * 384 + sl2 * 8];
      bf16x8 hv;
      #pragma unroll
      for (int k = 0; k < 8; ++k) {
        float rr = sigf(b2f((u16)ir8[k]) + b2f((u16)hr8[k]));
        float zz = sigf(b2f((u16)iz8[k]) + b2f((u16)hz8[k]));
        float nn = tanhf(b2f((u16)in8[k]) + rr * b2f((u16)hn8[k]));
        float h = (1.f - zz) * nn + zz * hp[q][k];
        hp[q][k] = h;
        hv[k] = (short)f2b(h);
      }
      *(bf16x8*)&hA[cr * 128 + ((c0 >> 3) ^ (cr & 7)) * 8] = hv;
      *(bf16x8*)&ctx_t[cb + c0] = hv;
    }
    __syncthreads();
  }
}

// ---------------------------------------------------------------------------
// Temporal attention middle: scores + softmax + mix. One wave / node.
// ---------------------------------------------------------------------------
__global__ __launch_bounds__(256) void attn_mid(
    const u16* __restrict__ ctx, const float* __restrict__ q,
    u16* __restrict__ comb)
{
  const int node = blockIdx.x * 4 + (threadIdx.x >> 6);
  const int lane = threadIdx.x & 63;
  if (node >= N_NODES) return;
  const float q0 = q[(size_t)node * GHD + lane];
  const float q1 = q[(size_t)node * GHD + 64 + lane];
  float c0[T_STEPS], c1[T_STEPS], w[T_STEPS];
  float mx = -1e30f;
  #pragma unroll
  for (int t = 0; t < T_STEPS; ++t) {
    const u16* cr = ctx + ((size_t)t * N_NODES + node) * GHD;
    c0[t] = b2f(cr[lane]); c1[t] = b2f(cr[64 + lane]);
    float p = q0 * c0[t] + q1 * c1[t];
    #pragma unroll
    for (int m = 32; m >= 1; m >>= 1) p += __shfl_xor(p, m);
    w[t] = p;
    mx = fmaxf(mx, p);
  }
  float s = 0.f;
  #pragma unroll
  for (int t = 0; t < T_STEPS; ++t) { w[t] = expf(w[t] - mx); s += w[t]; }
  const float inv = 1.f / s;
  float m0 = 0.f, m1 = 0.f;
  #pragma unroll
  for (int t = 0; t < T_STEPS; ++t) { m0 = fmaf(w[t], c0[t], m0); m1 = fmaf(w[t], c1[t], m1); }
  m0 *= inv; m1 *= inv;
  u16* cb = comb + (size_t)node * 2 * GHD;
  cb[lane]       = f2b(m0);
  cb[64 + lane]  = f2b(m1);
  cb[128 + lane] = f2b(q0);
  cb[192 + lane] = f2b(q1);
}

// ---------------------------------------------------------------------------
extern "C" void kernel_launch(void* const* d_in, const int* in_sizes, int n_in,
                              void* d_out, int out_size, void* d_ws, size_t ws_size,
                              hipStream_t stream)
{
  const int*   graph     = (const int*)  d_in[0];
  const float* fts       = (const float*)d_in[1];
  const float* W_gat     = (const float*)d_in[3];
  const float* att_src   = (const float*)d_in[4];
  const float* att_dst   = (const float*)d_in[5];
  const float* b_gat     = (const float*)d_in[6];
  const float* W_ih      = (const float*)d_in[7];
  const float* W_hh      = (const float*)d_in[8];
  const float* b_ih      = (const float*)d_in[9];
  const float* b_hh      = (const float*)d_in[10];
  const float* W_att_in  = (const float*)d_in[11];
  const float* W_att_out = (const float*)d_in[12];
  const float* W_cls     = (const float*)d_in[13];
  const float* b_cls     = (const float*)d_in[14];
  float* out = (float*)d_out;

  char* ws = (char*)d_ws;
  size_t off = 0;
  auto alloc = [&](size_t bytes) {
    void* p = ws + off;
    off = (off + bytes + 255) & ~(size_t)255;
    return p;
  };
  const size_t NT = (size_t)TN;                    // 160000 rows
  u16*   wgatT = (u16*)alloc((size_t)KC * F_INC * 2);
  u16*   wihb  = (u16*)alloc((size_t)G3 * GHD * 2);
  u16*   whhb  = (u16*)alloc((size_t)G3 * GHD * 2);
  u16*   winb  = (u16*)alloc((size_t)GHD * GHD * 2);
  u16*   woutb = (u16*)alloc((size_t)GHD * 2 * GHD * 2);
  u16*   xw    = (u16*)alloc(NT * KC * 2);          // 164 MB
  float* asrc  = (float*)alloc(NT * 4 * 4);
  float* adst  = (float*)alloc(NT * 4 * 4);
  u16*   yall  = (u16*)alloc(NT * GHD * 2);         // 41 MB
  u16*   ctx   = (u16*)alloc(NT * GHD * 2);         // 41 MB
  float* qf    = (float*)alloc((size_t)N_NODES * GHD * 4);
  u16*   comb  = (u16*)alloc((size_t)N_NODES * 2 * GHD * 2);
  int* counts  = (int*)alloc((size_t)2 * TN * 4);   // counts + cursor
  int* cursor  = counts + TN;
  int* offs    = (int*)alloc((size_t)(TN + 1) * 4);
  int* bsums   = (int*)alloc((size_t)256 * 4);
  int* ssrc    = (int*)alloc((size_t)T_STEPS * SEG * 4);

  // weight converts
  conv_transpose_wgat<<<dim3((KC * F_INC + 255) / 256), 256, 0, stream>>>(W_gat, wgatT);
  convert_weights<<<dim3(72), 256, 0, stream>>>(W_ih, W_hh, W_att_in, W_att_out,
                                                wihb, whhb, winb, woutb);

  // batched edge sort (flat 3-phase scan)
  hipMemsetAsync(counts, 0, (size_t)2 * TN * 4, stream);
  count_kernel<<<dim3(N_EDGES / 256, T_STEPS), 256, 0, stream>>>(graph, counts);
  scanA<<<dim3(SCAN_BLKS), 1024, 0, stream>>>(counts, offs, bsums);
  scanB<<<dim3(1), 64, 0, stream>>>(bsums, offs);
  scanC<<<dim3(SCAN_BLKS), 1024, 0, stream>>>(offs, bsums);
  scatter_kernel<<<dim3((SEG + 255) / 256, T_STEPS), 256, 0, stream>>>(graph, offs, cursor, ssrc);

  // xw = fts(fp32) @ W_gat^T for ALL t (convert fused) + fused a_src/a_dst
  gemm_bf16<1, 1, 1><<<dim3(KC / 128, (int)(NT / 128)), 256, 0, stream>>>(
      fts, wgatT, nullptr, xw, (int)NT, F_INC, KC, 1, att_src, att_dst, asrc, adst);

  // batched aggregate -> y for ALL t
  aggregate_kernel<<<dim3(N_NODES / 4, T_STEPS), 256, 0, stream>>>(
      xw, asrc, adst, b_gat, offs, ssrc, yall);

  // fully-fused GRU (gi + gh + combine, all 8 steps, one kernel)
  gru_seq<<<dim3(N_NODES / 32), 256, 0, stream>>>(whhb, wihb, b_hh, b_ih, yall, ctx);

  // temporal attention tail
  gemm_bf16<0, 0, 0><<<dim3(1, (N_NODES + 127) / 128), 256, 0, stream>>>(
      ctx + (size_t)(T_STEPS - 1) * N_NODES * GHD, winb, nullptr, qf,
      N_NODES, GHD, GHD, 0, nullptr, nullptr, nullptr, nullptr);
  attn_mid<<<dim3(N_NODES / 4), 256, 0, stream>>>(ctx, qf, comb);
  // out-GEMM with fused classifier + log_softmax (writes d_out directly)
  gemm_bf16<0, 2, 0><<<dim3(1, (N_NODES + 127) / 128), 256, 0, stream>>>(
      comb, woutb, b_cls, nullptr, N_NODES, 2 * GHD, GHD, 0,
      W_cls, W_cls + GHD, out, nullptr);
}

// Round 10
// 724.603 us; speedup vs baseline: 1.0289x; 1.0289x over previous
//
#include <hip/hip_runtime.h>
#include <hip/hip_bf16.h>
#include <math.h>

#define N_NODES 20000
#define N_EDGES 160000
#define T_STEPS 8
#define F_INC   256
#define HEADS   4
#define CCH     128
#define KC      512   // HEADS*CCH
#define GHD     128
#define G3      384
#define SLOPE   0.2f
#define SEG     (N_EDGES + N_NODES)   // edges + self loops per t
#define TN      (T_STEPS * N_NODES)   // 160000
#define SCAN_BLKS ((TN + 1023) / 1024)  // 157

typedef unsigned short u16;
typedef __attribute__((ext_vector_type(8))) short bf16x8;
typedef __attribute__((ext_vector_type(4))) float f32x4;

__device__ __forceinline__ float leakyf(float x) { return x > 0.f ? x : SLOPE * x; }
__device__ __forceinline__ float b2f(u16 u) {
  union { unsigned int i; float f; } x; x.i = ((unsigned int)u) << 16; return x.f;
}
__device__ __forceinline__ u16 f2b(float f) {
  union { float f; unsigned int i; } u; u.f = f;
  unsigned int r = u.i + 0x7FFFu + ((u.i >> 16) & 1u);
  return (u16)(r >> 16);
}
__device__ __forceinline__ float sigf(float x) { return 1.f / (1.f + expf(-x)); }

// async global->LDS 16B (wave-uniform LDS base + lane*16; per-lane global src)
__device__ __forceinline__ void gload16(const void* g, void* l) {
  __builtin_amdgcn_global_load_lds(
      (const __attribute__((address_space(1))) unsigned int*)g,
      (__attribute__((address_space(3))) unsigned int*)l, 16, 0, 0);
}

// pack 8 f32 -> bf16x8 via v_cvt_pk_bf16_f32 (no builtin on gfx950)
__device__ __forceinline__ bf16x8 cvt8(f32x4 lo, f32x4 hi) {
  union { unsigned int u[4]; bf16x8 v; } r;
  asm("v_cvt_pk_bf16_f32 %0, %1, %2" : "=v"(r.u[0]) : "v"(lo[0]), "v"(lo[1]));
  asm("v_cvt_pk_bf16_f32 %0, %1, %2" : "=v"(r.u[1]) : "v"(lo[2]), "v"(lo[3]));
  asm("v_cvt_pk_bf16_f32 %0, %1, %2" : "=v"(r.u[2]) : "v"(hi[0]), "v"(hi[1]));
  asm("v_cvt_pk_bf16_f32 %0, %1, %2" : "=v"(r.u[3]) : "v"(hi[2]), "v"(hi[3]));
  return r.v;
}

// ---------------------------------------------------------------------------
// bf16 MFMA GEMM: C[M,Nt] = A[M,K] @ B^T (+bias). B (Nt,K) bf16.
// AFP32=1: A fp32, converted at fragment-read (v_cvt_pk_bf16_f32).
// FUSE=1: fused a_src/a_dst row-dots (xw gemm).
// FUSE=2: fused classifier: o=leaky(tanh(C)), logits=o@W_cls^T + b_cls,
//         log_softmax -> out (no C write).
// ---------------------------------------------------------------------------
template <int OBF, int FUSE, int AFP32>
__global__ __launch_bounds__(256) void gemm_bf16(
    const void* __restrict__ Ain, const u16* __restrict__ B,
    const float* __restrict__ bias, void* __restrict__ Cout,
    int M, int K, int Nt, int swz,
    const float* __restrict__ attS, const float* __restrict__ attD,
    float* __restrict__ asrc, float* __restrict__ adst)
{
  __shared__ __align__(16) char AsRaw[128 * 32 * 4];
  __shared__ u16 Bs[128][32];
  __shared__ float s_as[128], s_ad[128];
  float* AsF = (float*)AsRaw;
  u16 (*Asb)[32] = (u16(*)[32])AsRaw;
  const int tid  = threadIdx.x;
  const int wave = tid >> 6, lane = tid & 63;
  const int wr = (wave >> 1) * 64, wc = (wave & 1) * 64;
  int bx = blockIdx.x, by = blockIdx.y;
  if (swz) {
    const int gx = gridDim.x;
    const int nwg = gx * (int)gridDim.y;
    const int lin = by * gx + bx;
    const int q = nwg >> 3, r = nwg & 7;
    const int xcd = lin & 7, idx = lin >> 3;
    const int wg = (xcd < r ? xcd * (q + 1) : r * (q + 1) + (xcd - r) * q) + idx;
    bx = wg % gx; by = wg / gx;
  }
  const int bm = by * 128, bn = bx * 128;
  const int l15 = lane & 15, g = lane >> 4;

  if (FUSE && tid < 128) { s_as[tid] = 0.f; s_ad[tid] = 0.f; }

  const int sr = tid >> 2, sd = tid & 3;
  const int ss = sd ^ ((sr >> 1) & 3);
  const u16* aS0 = 0; const u16* aS1 = 0; u16* lA0 = 0; u16* lA1 = 0;
  const float* aF[4]; float* lAF[4];
  if (AFP32) {
    const float* Af = (const float*)Ain;
    const int row0 = tid >> 3, sd8 = tid & 7;
    const int ss8 = sd8 ^ (row0 & 7);
    #pragma unroll
    for (int p = 0; p < 4; ++p) {
      int row = row0 + p * 32;
      aF[p] = Af + (size_t)min(bm + row, M - 1) * K + ss8 * 4;
      lAF[p] = AsF + (size_t)(p * 256 + (tid & ~63)) * 4;
    }
  } else {
    const u16* Ab = (const u16*)Ain;
    aS0 = Ab + (size_t)min(bm + sr,      M - 1) * K + ss * 8;
    aS1 = Ab + (size_t)min(bm + 64 + sr, M - 1) * K + ss * 8;
    lA0 = (u16*)AsRaw + (size_t)(tid & ~63) * 8;
    lA1 = lA0 + 2048;
  }
  const u16* bS0 = B + (size_t)(bn + sr)      * K + ss * 8;
  const u16* bS1 = B + (size_t)(bn + 64 + sr) * K + ss * 8;
  u16* lB0 = &Bs[0][0] + (size_t)(tid & ~63) * 8;
  u16* lB1 = lB0 + 2048;

  f32x4 acc[4][4];
  #pragma unroll
  for (int m = 0; m < 4; ++m)
    #pragma unroll
    for (int n = 0; n < 4; ++n)
      #pragma unroll
      for (int j = 0; j < 4; ++j) acc[m][n][j] = 0.f;

  const int nK = K >> 5;
  for (int kt = 0; kt < nK; ++kt) {
    const int ko = kt * 32;
    if (AFP32) {
      #pragma unroll
      for (int p = 0; p < 4; ++p) gload16(aF[p] + ko, lAF[p]);
    } else {
      gload16(aS0 + ko, lA0);
      gload16(aS1 + ko, lA1);
    }
    gload16(bS0 + ko, lB0);
    gload16(bS1 + ko, lB1);
    __syncthreads();
    bf16x8 af[4], bfr[4];
    #pragma unroll
    for (int m = 0; m < 4; ++m) {
      int row = wr + m * 16 + l15;
      if (AFP32) {
        int s0 = (2 * g) ^ (row & 7), s1 = (2 * g + 1) ^ (row & 7);
        f32x4 lo = *(const f32x4*)&AsF[row * 32 + s0 * 4];
        f32x4 hi = *(const f32x4*)&AsF[row * 32 + s1 * 4];
        af[m] = cvt8(lo, hi);
      } else {
        af[m] = *(const bf16x8*)&Asb[row][(g ^ ((row >> 1) & 3)) * 8];
      }
      int rowb = wc + m * 16 + l15;
      bfr[m] = *(const bf16x8*)&Bs[rowb][(g ^ ((rowb >> 1) & 3)) * 8];
    }
    #pragma unroll
    for (int m = 0; m < 4; ++m)
      #pragma unroll
      for (int n = 0; n < 4; ++n)
        acc[m][n] = __builtin_amdgcn_mfma_f32_16x16x32_bf16(af[m], bfr[n], acc[m][n], 0, 0, 0);
    __syncthreads();
  }
  if (FUSE != 2) {
    #pragma unroll
    for (int m = 0; m < 4; ++m) {
      int row0 = bm + wr + m * 16 + g * 4;
      #pragma unroll
      for (int n = 0; n < 4; ++n) {
        int col = bn + wc + n * 16 + l15;
        float bv = bias ? bias[col] : 0.f;
        #pragma unroll
        for (int j = 0; j < 4; ++j) {
          int row = row0 + j;
          if (row < M) {
            float v = acc[m][n][j] + bv;
            if (OBF) ((u16*)Cout)[(size_t)row * Nt + col] = f2b(v);
            else     ((float*)Cout)[(size_t)row * Nt + col] = v;
          }
        }
      }
    }
  }
  if (FUSE) {
    float ps[4][4], pd[4][4];
    #pragma unroll
    for (int m = 0; m < 4; ++m)
      #pragma unroll
      for (int j = 0; j < 4; ++j) { ps[m][j] = 0.f; pd[m][j] = 0.f; }
    #pragma unroll
    for (int n = 0; n < 4; ++n) {
      int cl = wc + n * 16 + l15;
      float wsv = attS[bn + cl], wdv = attD[bn + cl];
      #pragma unroll
      for (int m = 0; m < 4; ++m)
        #pragma unroll
        for (int j = 0; j < 4; ++j) {
          float av = acc[m][n][j];
          if (FUSE == 2) av = leakyf(tanhf(av));
          ps[m][j] = fmaf(av, wsv, ps[m][j]);
          pd[m][j] = fmaf(av, wdv, pd[m][j]);
        }
    }
    #pragma unroll
    for (int m = 0; m < 4; ++m)
      #pragma unroll
      for (int j = 0; j < 4; ++j)
        #pragma unroll
        for (int msk = 8; msk >= 1; msk >>= 1) {
          ps[m][j] += __shfl_xor(ps[m][j], msk);
          pd[m][j] += __shfl_xor(pd[m][j], msk);
        }
    if (l15 == 0) {
      #pragma unroll
      for (int m = 0; m < 4; ++m)
        #pragma unroll
        for (int j = 0; j < 4; ++j) {
          atomicAdd(&s_as[wr + m * 16 + g * 4 + j], ps[m][j]);
          atomicAdd(&s_ad[wr + m * 16 + g * 4 + j], pd[m][j]);
        }
    }
    __syncthreads();
    if (tid < 128) {
      int row = bm + tid;
      if (row < M) {
        if (FUSE == 1) {
          int h = bn >> 7;
          asrc[(size_t)row * 4 + h] = s_as[tid];
          adst[(size_t)row * 4 + h] = s_ad[tid];
        } else {
          float l0 = s_as[tid] + bias[0];
          float l1 = s_ad[tid] + bias[1];
          float mx = fmaxf(l0, l1);
          float lse = mx + logf(expf(l0 - mx) + expf(l1 - mx));
          asrc[(size_t)row * 2 + 0] = l0 - lse;
          asrc[(size_t)row * 2 + 1] = l1 - lse;
        }
      }
    }
  }
}

// ---------------------------------------------------------------------------
// merged small-weight converts: W_ih, W_hh, W_att_in, W_att_out (8 elems/thr)
// ---------------------------------------------------------------------------
__global__ void convert_weights(const float* __restrict__ w_ih, const float* __restrict__ w_hh,
                                const float* __restrict__ w_in, const float* __restrict__ w_out,
                                u16* __restrict__ wihb, u16* __restrict__ whhb,
                                u16* __restrict__ winb, u16* __restrict__ woutb)
{
  int i = blockIdx.x * 256 + threadIdx.x;   // 18432 threads
  const float* src; u16* dst; int base;
  if      (i < 6144)  { src = w_ih;  dst = wihb;  base = i; }
  else if (i < 12288) { src = w_hh;  dst = whhb;  base = i - 6144; }
  else if (i < 14336) { src = w_in;  dst = winb;  base = i - 12288; }
  else                { src = w_out; dst = woutb; base = i - 14336; }
  int o = base * 8;
  float4 v0 = *(const float4*)(src + o);
  float4 v1 = *(const float4*)(src + o + 4);
  bf16x8 ov;
  ov[0] = (short)f2b(v0.x); ov[1] = (short)f2b(v0.y);
  ov[2] = (short)f2b(v0.z); ov[3] = (short)f2b(v0.w);
  ov[4] = (short)f2b(v1.x); ov[5] = (short)f2b(v1.y);
  ov[6] = (short)f2b(v1.z); ov[7] = (short)f2b(v1.w);
  *(bf16x8*)(dst + o) = ov;
}

__global__ void conv_transpose_wgat(const float* __restrict__ src, u16* __restrict__ dst) {
  int idx = blockIdx.x * 256 + threadIdx.x;
  if (idx >= KC * F_INC) return;
  int n = idx >> 8, k = idx & 255;
  dst[(size_t)n * F_INC + k] = f2b(src[(size_t)k * KC + n]);
}

// ---------------------------------------------------------------------------
// Batched edge counting-sort (all T at once). offs = FLAT global scan of
// (counts+1) over all T*N nodes; per-t bases (t*SEG) emerge automatically.
// ---------------------------------------------------------------------------
__global__ void count_kernel(const int* __restrict__ graph, int* __restrict__ counts) {
  int e = blockIdx.x * 256 + threadIdx.x;
  int t = blockIdx.y;
  if (e < N_EDGES) {
    int d = graph[(size_t)t * 2 * N_EDGES + N_EDGES + e];
    atomicAdd(&counts[t * N_NODES + d], 1);
  }
}

__global__ __launch_bounds__(1024) void scanA(
    const int* __restrict__ counts, int* __restrict__ offs, int* __restrict__ bsums)
{
  const int tid = threadIdx.x, lane = tid & 63, w = tid >> 6;
  __shared__ int s_wt[16];
  int i = blockIdx.x * 1024 + tid;
  int v = (i < TN) ? (counts[i] + 1) : 0;   // +1 self loop
  int x = v;
  #pragma unroll
  for (int d = 1; d < 64; d <<= 1) {
    int nvl = __shfl_up(x, d, 64);
    if (lane >= d) x += nvl;
  }
  if (lane == 63) s_wt[w] = x;
  __syncthreads();
  if (tid < 16) {
    int y = s_wt[tid];
    #pragma unroll
    for (int d = 1; d < 16; d <<= 1) {
      int nvl = __shfl_up(y, d, 64);
      if (tid >= d) y += nvl;
    }
    s_wt[tid] = y;
  }
  __syncthreads();
  int wbase = (w > 0) ? s_wt[w - 1] : 0;
  if (i < TN) offs[i] = wbase + x - v;       // block-local exclusive
  if (tid == 1023) bsums[blockIdx.x] = s_wt[15];
}

__global__ void scanB(int* __restrict__ bsums, int* __restrict__ offs) {
  const int lane = threadIdx.x;  // 64 threads, 1 block
  int carry = 0;
  for (int base = 0; base < 192; base += 64) {
    int idx = base + lane;
    int v = (idx < SCAN_BLKS) ? bsums[idx] : 0;
    int x = v;
    #pragma unroll
    for (int d = 1; d < 64; d <<= 1) {
      int nvl = __shfl_up(x, d, 64);
      if (lane >= d) x += nvl;
    }
    if (idx < SCAN_BLKS) bsums[idx] = carry + x - v;   // exclusive
    carry += __shfl(x, 63);
  }
  if (lane == 0) offs[TN] = carry;   // == T_STEPS * SEG
}

__global__ __launch_bounds__(1024) void scanC(int* __restrict__ offs, const int* __restrict__ bsums) {
  int i = blockIdx.x * 1024 + threadIdx.x;
  if (i < TN) offs[i] += bsums[blockIdx.x];
}

__global__ void scatter_kernel(const int* __restrict__ graph, const int* __restrict__ offs,
                               int* __restrict__ cursor, int* __restrict__ ssrc)
{
  int i = blockIdx.x * 256 + threadIdx.x;
  int t = blockIdx.y;
  if (i >= SEG) return;
  int s, d;
  if (i < N_EDGES) {
    s = graph[(size_t)t * 2 * N_EDGES + i];
    d = graph[(size_t)t * 2 * N_EDGES + N_EDGES + i];
  } else {
    s = d = i - N_EDGES;
  }
  int pos = offs[t * N_NODES + d] + atomicAdd(&cursor[t * N_NODES + d], 1);
  ssrc[pos] = s;
}

// ---------------------------------------------------------------------------
// Batched aggregate (proven round-7 structure; flat offs indexing).
// ---------------------------------------------------------------------------
__global__ __launch_bounds__(256) void aggregate_kernel(
    const u16* __restrict__ xw, const float* __restrict__ a_src,
    const float* __restrict__ a_dst, const float* __restrict__ b_gat,
    const int* __restrict__ offs, const int* __restrict__ ssrc,
    u16* __restrict__ yout)
{
  const int wv = threadIdx.x >> 6, lane = threadIdx.x & 63;
  const int nd = blockIdx.x * 4 + wv;
  const int t  = blockIdx.y;
  const int ob = t * N_NODES + nd;
  const int beg = offs[ob], end = offs[ob + 1];
  const size_t rowbase = (size_t)t * N_NODES;
  const int he   = lane & 3;
  const int eidx = lane >> 2;
  const int hl   = lane >> 4;
  const float advh = a_dst[(rowbase + nd) * 4 + he];

  float m = -INFINITY, ssum = 0.f;
  float acc[8] = {0.f,0.f,0.f,0.f,0.f,0.f,0.f,0.f};

#define FMA8(W, X)                                                        \
    { float _w = (W);                                                     \
      acc[0] = fmaf(_w, __uint_as_float((unsigned)(X).x << 16), acc[0]);  \
      acc[1] = fmaf(_w, __uint_as_float((unsigned)(X).x & 0xffff0000u), acc[1]); \
      acc[2] = fmaf(_w, __uint_as_float((unsigned)(X).y << 16), acc[2]);  \
      acc[3] = fmaf(_w, __uint_as_float((unsigned)(X).y & 0xffff0000u), acc[3]); \
      acc[4] = fmaf(_w, __uint_as_float((unsigned)(X).z << 16), acc[4]);  \
      acc[5] = fmaf(_w, __uint_as_float((unsigned)(X).z & 0xffff0000u), acc[5]); \
      acc[6] = fmaf(_w, __uint_as_float((unsigned)(X).w << 16), acc[6]);  \
      acc[7] = fmaf(_w, __uint_as_float((unsigned)(X).w & 0xffff0000u), acc[7]); }
#define LDE(SVAR) (*(const int4*)&xw[(rowbase + (SVAR)) * KC + lane * 8])

  for (int base = beg; base < end; base += 16) {
    const int cnt = min(16, end - base);
    const int e = base + eidx;
    const int sidx = (e < end) ? ssrc[e] : ssrc[base];
    const float av = a_src[(rowbase + sidx) * 4 + he];
    const float a = (eidx < cnt) ? leakyf(av + advh) : -INFINITY;
    float cm = a;
    cm = fmaxf(cm, __shfl_xor(cm, 4));
    cm = fmaxf(cm, __shfl_xor(cm, 8));
    cm = fmaxf(cm, __shfl_xor(cm, 16));
    cm = fmaxf(cm, __shfl_xor(cm, 32));
    const float nm = fmaxf(m, cm);
    const float sc = expf(m - nm);
    const float w = expf(a - nm);
    float ts = w;
    ts += __shfl_xor(ts, 4);
    ts += __shfl_xor(ts, 8);
    ts += __shfl_xor(ts, 16);
    ts += __shfl_xor(ts, 32);
    ssum = ssum * sc + ts;
    m = nm;
    const float schl = __shfl(sc, hl);
    #pragma unroll
    for (int k = 0; k < 8; ++k) acc[k] *= schl;

    const int cpad = (cnt + 3) & ~3;
    int b4 = 0;
    for (; b4 + 8 <= cpad; b4 += 8) {
      const int s0 = __shfl(sidx, (b4 + 0) << 2);
      const int s1 = __shfl(sidx, (b4 + 1) << 2);
      const int s2 = __shfl(sidx, (b4 + 2) << 2);
      const int s3 = __shfl(sidx, (b4 + 3) << 2);
      const int s4 = __shfl(sidx, (b4 + 4) << 2);
      const int s5 = __shfl(sidx, (b4 + 5) << 2);
      const int s6 = __shfl(sidx, (b4 + 6) << 2);
      const int s7 = __shfl(sidx, (b4 + 7) << 2);
      const int4 x0 = LDE(s0); const int4 x1 = LDE(s1);
      const int4 x2 = LDE(s2); const int4 x3 = LDE(s3);
      const int4 x4 = LDE(s4); const int4 x5 = LDE(s5);
      const int4 x6 = LDE(s6); const int4 x7 = LDE(s7);
      const float w0 = __shfl(w, ((b4 + 0) << 2) + hl);
      const float w1 = __shfl(w, ((b4 + 1) << 2) + hl);
      const float w2 = __shfl(w, ((b4 + 2) << 2) + hl);
      const float w3 = __shfl(w, ((b4 + 3) << 2) + hl);
      const float w4 = __shfl(w, ((b4 + 4) << 2) + hl);
      const float w5 = __shfl(w, ((b4 + 5) << 2) + hl);
      const float w6 = __shfl(w, ((b4 + 6) << 2) + hl);
      const float w7 = __shfl(w, ((b4 + 7) << 2) + hl);
      FMA8(w0, x0); FMA8(w1, x1); FMA8(w2, x2); FMA8(w3, x3);
      FMA8(w4, x4); FMA8(w5, x5); FMA8(w6, x6); FMA8(w7, x7);
    }
    if (b4 < cpad) {
      const int s0 = __shfl(sidx, (b4 + 0) << 2);
      const int s1 = __shfl(sidx, (b4 + 1) << 2);
      const int s2 = __shfl(sidx, (b4 + 2) << 2);
      const int s3 = __shfl(sidx, (b4 + 3) << 2);
      const int4 x0 = LDE(s0); const int4 x1 = LDE(s1);
      const int4 x2 = LDE(s2); const int4 x3 = LDE(s3);
      const float w0 = __shfl(w, ((b4 + 0) << 2) + hl);
      const float w1 = __shfl(w, ((b4 + 1) << 2) + hl);
      const float w2 = __shfl(w, ((b4 + 2) << 2) + hl);
      const float w3 = __shfl(w, ((b4 + 3) << 2) + hl);
      FMA8(w0, x0); FMA8(w1, x1); FMA8(w2, x2); FMA8(w3, x3);
    }
  }
#undef LDE
#undef FMA8

  const float sh = __shfl(ssum, hl);
  const float inv = 1.f / (sh + 1e-16f);
  #pragma unroll
  for (int k = 0; k < 8; ++k) {
    acc[k] *= inv;
    acc[k] += __shfl_xor(acc[k], 16);
    acc[k] += __shfl_xor(acc[k], 32);
  }
  if (lane < 16) {
    bf16x8 ov;
    #pragma unroll
    for (int k = 0; k < 8; ++k) {
      float v = acc[k] * 0.25f + b_gat[lane * 8 + k];
      ov[k] = (short)f2b(leakyf(v));
    }
    *(bf16x8*)&yout[(rowbase + nd) * GHD + lane * 8] = ov;
  }
}

// ---------------------------------------------------------------------------
// Fused GRU recurrence (round-8 proven): ONE kernel, 625 blocks x 32 rows,
// gh-GEMM only (gi precomputed). h carried fp32 in registers + bf16 in
// swizzled LDS hA; W_hh per-kt via global_load_lds; gh restaged through LDS.
// 32 KB LDS total.
// ---------------------------------------------------------------------------
__global__ __launch_bounds__(256) void gru_seq(
    const u16* __restrict__ Whh, const float* __restrict__ b_hh,
    const u16* __restrict__ giall, u16* __restrict__ ctx)
{
  __shared__ u16 hA[32][128];       // 8 KB: h bf16, slot^=(row&7) swizzle
  __shared__ u16 reg2[12288];       // 24 KB: Bs (384x32) during MFMA, gh after
  u16 (*Bs)[32] = (u16(*)[32])reg2;
  const int tid = threadIdx.x, lane = tid & 63, wv = tid >> 6;
  const int l15 = lane & 15, g = lane >> 4;
  const int bm = blockIdx.x * 32;   // 20000 = 625*32, no tail

  const int sr = tid >> 2, sd = tid & 3;
  const int ssb = sd ^ ((sr >> 1) & 3);
  const u16* bS[6]; u16* lB[6];
  #pragma unroll
  for (int p = 0; p < 6; ++p) {
    bS[p] = Whh + (size_t)(sr + p * 64) * GHD + ssb * 8;
    lB[p] = reg2 + (size_t)(p * 256 + (tid & ~63)) * 8;
  }
  float bbv[6];
  #pragma unroll
  for (int n = 0; n < 6; ++n) bbv[n] = b_hh[wv * 96 + n * 16 + l15];

  const int cr = tid >> 3;
  const int cg = (tid & 7) * 8;
  const int grow = bm + cr;
  const size_t gb = (size_t)grow * G3;
  const size_t cb = (size_t)grow * GHD;
  float hp[2][8];

  // ---- t = 0: h = (1-z)*tanh(i_n + r*b_hh_n), gh == b_hh ----
  #pragma unroll
  for (int q = 0; q < 2; ++q) {
    const int c0 = cg + q * 64;
    bf16x8 ir8 = *(const bf16x8*)&giall[gb + c0];
    bf16x8 iz8 = *(const bf16x8*)&giall[gb + 128 + c0];
    bf16x8 in8 = *(const bf16x8*)&giall[gb + 256 + c0];
    float4 br0 = *(const float4*)&b_hh[c0];       float4 br1 = *(const float4*)&b_hh[c0 + 4];
    float4 bz0 = *(const float4*)&b_hh[128 + c0]; float4 bz1 = *(const float4*)&b_hh[128 + c0 + 4];
    float4 bn0 = *(const float4*)&b_hh[256 + c0]; float4 bn1 = *(const float4*)&b_hh[256 + c0 + 4];
    float bhr[8] = {br0.x, br0.y, br0.z, br0.w, br1.x, br1.y, br1.z, br1.w};
    float bhz[8] = {bz0.x, bz0.y, bz0.z, bz0.w, bz1.x, bz1.y, bz1.z, bz1.w};
    float bhn[8] = {bn0.x, bn0.y, bn0.z, bn0.w, bn1.x, bn1.y, bn1.z, bn1.w};
    bf16x8 hv;
    #pragma unroll
    for (int k = 0; k < 8; ++k) {
      float rr = sigf(b2f((u16)ir8[k]) + bhr[k]);
      float zz = sigf(b2f((u16)iz8[k]) + bhz[k]);
      float nn = tanhf(b2f((u16)in8[k]) + rr * bhn[k]);
      float h = (1.f - zz) * nn;
      hp[q][k] = h;
      hv[k] = (short)f2b(h);
    }
    const int sl = (c0 >> 3) ^ (cr & 7);
    *(bf16x8*)&hA[cr][sl * 8] = hv;
    *(bf16x8*)&ctx[cb + c0] = hv;
  }
  __syncthreads();

  // ---- t = 1..7 ----
  for (int t = 1; t < T_STEPS; ++t) {
    const u16* gi_t = giall + (size_t)t * N_NODES * G3;
    u16* ctx_t = ctx + (size_t)t * N_NODES * GHD;
    f32x4 acc[2][6];
    #pragma unroll
    for (int m = 0; m < 2; ++m)
      #pragma unroll
      for (int n = 0; n < 6; ++n)
        #pragma unroll
        for (int j = 0; j < 4; ++j) acc[m][n][j] = 0.f;

    #pragma unroll
    for (int kt = 0; kt < 4; ++kt) {
      const int ko = kt * 32;
      #pragma unroll
      for (int p = 0; p < 6; ++p) gload16(bS[p] + ko, lB[p]);
      __syncthreads();
      bf16x8 af[2], bfr[6];
      #pragma unroll
      for (int m = 0; m < 2; ++m) {
        int row = m * 16 + l15;
        int sl = (kt * 4 + g) ^ (row & 7);
        af[m] = *(const bf16x8*)&hA[row][sl * 8];
      }
      #pragma unroll
      for (int n = 0; n < 6; ++n) {
        int rowb = wv * 96 + n * 16 + l15;
        bfr[n] = *(const bf16x8*)&Bs[rowb][(g ^ ((rowb >> 1) & 3)) * 8];
      }
      #pragma unroll
      for (int m = 0; m < 2; ++m)
        #pragma unroll
        for (int n = 0; n < 6; ++n)
          acc[m][n] = __builtin_amdgcn_mfma_f32_16x16x32_bf16(af[m], bfr[n], acc[m][n], 0, 0, 0);
      __syncthreads();
    }
    // stage gh (+b_hh) into reg2 (clobbers Bs; all reads done)
    #pragma unroll
    for (int m = 0; m < 2; ++m)
      #pragma unroll
      for (int n = 0; n < 6; ++n) {
        int c = wv * 96 + n * 16 + l15;
        #pragma unroll
        for (int j = 0; j < 4; ++j) {
          int r = m * 16 + g * 4 + j;
          reg2[r * 384 + (((c >> 3) ^ (r & 7)) << 3) + (c & 7)] = f2b(acc[m][n][j] + bbv[n]);
        }
      }
    __syncthreads();
    // combine (reads reg2, writes hA + ctx; hp carries fp32 state)
    #pragma unroll
    for (int q = 0; q < 2; ++q) {
      const int c0 = cg + q * 64;
      const int sl0 = ((c0 >> 3) ^ (cr & 7));
      const int sl1 = (((128 + c0) >> 3) ^ (cr & 7));
      const int sl2 = (((256 + c0) >> 3) ^ (cr & 7));
      bf16x8 hr8 = *(bf16x8*)&reg2[cr * 384 + sl0 * 8];
      bf16x8 hz8 = *(bf16x8*)&reg2[cr * 384 + sl1 * 8];
      bf16x8 hn8 = *(bf16x8*)&reg2[cr * 384 + sl2 * 8];
      bf16x8 ir8 = *(const bf16x8*)&gi_t[gb + c0];
      bf16x8 iz8 = *(const bf16x8*)&gi_t[gb + 128 + c0];
      bf16x8 in8 = *(const bf16x8*)&gi_t[gb + 256 + c0];
      bf16x8 hv;
      #pragma unroll
      for (int k = 0; k < 8; ++k) {
        float rr = sigf(b2f((u16)ir8[k]) + b2f((u16)hr8[k]));
        float zz = sigf(b2f((u16)iz8[k]) + b2f((u16)hz8[k]));
        float nn = tanhf(b2f((u16)in8[k]) + rr * b2f((u16)hn8[k]));
        float h = (1.f - zz) * nn + zz * hp[q][k];
        hp[q][k] = h;
        hv[k] = (short)f2b(h);
      }
      const int slh = (c0 >> 3) ^ (cr & 7);
      *(bf16x8*)&hA[cr][slh * 8] = hv;
      *(bf16x8*)&ctx_t[cb + c0] = hv;
    }
    __syncthreads();
  }
}

// ---------------------------------------------------------------------------
// Temporal attention middle: scores + softmax + mix. One wave / node.
// ---------------------------------------------------------------------------
__global__ __launch_bounds__(256) void attn_mid(
    const u16* __restrict__ ctx, const float* __restrict__ q,
    u16* __restrict__ comb)
{
  const int node = blockIdx.x * 4 + (threadIdx.x >> 6);
  const int lane = threadIdx.x & 63;
  if (node >= N_NODES) return;
  const float q0 = q[(size_t)node * GHD + lane];
  const float q1 = q[(size_t)node * GHD + 64 + lane];
  float c0[T_STEPS], c1[T_STEPS], w[T_STEPS];
  float mx = -1e30f;
  #pragma unroll
  for (int t = 0; t < T_STEPS; ++t) {
    const u16* cr = ctx + ((size_t)t * N_NODES + node) * GHD;
    c0[t] = b2f(cr[lane]); c1[t] = b2f(cr[64 + lane]);
    float p = q0 * c0[t] + q1 * c1[t];
    #pragma unroll
    for (int m = 32; m >= 1; m >>= 1) p += __shfl_xor(p, m);
    w[t] = p;
    mx = fmaxf(mx, p);
  }
  float s = 0.f;
  #pragma unroll
  for (int t = 0; t < T_STEPS; ++t) { w[t] = expf(w[t] - mx); s += w[t]; }
  const float inv = 1.f / s;
  float m0 = 0.f, m1 = 0.f;
  #pragma unroll
  for (int t = 0; t < T_STEPS; ++t) { m0 = fmaf(w[t], c0[t], m0); m1 = fmaf(w[t], c1[t], m1); }
  m0 *= inv; m1 *= inv;
  u16* cb = comb + (size_t)node * 2 * GHD;
  cb[lane]       = f2b(m0);
  cb[64 + lane]  = f2b(m1);
  cb[128 + lane] = f2b(q0);
  cb[192 + lane] = f2b(q1);
}

// ---------------------------------------------------------------------------
extern "C" void kernel_launch(void* const* d_in, const int* in_sizes, int n_in,
                              void* d_out, int out_size, void* d_ws, size_t ws_size,
                              hipStream_t stream)
{
  const int*   graph     = (const int*)  d_in[0];
  const float* fts       = (const float*)d_in[1];
  const float* W_gat     = (const float*)d_in[3];
  const float* att_src   = (const float*)d_in[4];
  const float* att_dst   = (const float*)d_in[5];
  const float* b_gat     = (const float*)d_in[6];
  const float* W_ih      = (const float*)d_in[7];
  const float* W_hh      = (const float*)d_in[8];
  const float* b_ih      = (const float*)d_in[9];
  const float* b_hh      = (const float*)d_in[10];
  const float* W_att_in  = (const float*)d_in[11];
  const float* W_att_out = (const float*)d_in[12];
  const float* W_cls     = (const float*)d_in[13];
  const float* b_cls     = (const float*)d_in[14];
  float* out = (float*)d_out;

  char* ws = (char*)d_ws;
  size_t off = 0;
  auto alloc = [&](size_t bytes) {
    void* p = ws + off;
    off = (off + bytes + 255) & ~(size_t)255;
    return p;
  };
  const size_t NT = (size_t)TN;                    // 160000 rows
  u16*   wgatT = (u16*)alloc((size_t)KC * F_INC * 2);
  u16*   wihb  = (u16*)alloc((size_t)G3 * GHD * 2);
  u16*   whhb  = (u16*)alloc((size_t)G3 * GHD * 2);
  u16*   winb  = (u16*)alloc((size_t)GHD * GHD * 2);
  u16*   woutb = (u16*)alloc((size_t)GHD * 2 * GHD * 2);
  u16*   xw    = (u16*)alloc(NT * KC * 2);          // 164 MB
  float* asrc  = (float*)alloc(NT * 4 * 4);
  float* adst  = (float*)alloc(NT * 4 * 4);
  u16*   yall  = (u16*)alloc(NT * GHD * 2);         // 41 MB
  u16*   giall = (u16*)alloc(NT * G3 * 2);          // 123 MB
  u16*   ctx   = (u16*)alloc(NT * GHD * 2);         // 41 MB
  float* qf    = (float*)alloc((size_t)N_NODES * GHD * 4);
  u16*   comb  = (u16*)alloc((size_t)N_NODES * 2 * GHD * 2);
  int* counts  = (int*)alloc((size_t)2 * TN * 4);   // counts + cursor
  int* cursor  = counts + TN;
  int* offs    = (int*)alloc((size_t)(TN + 1) * 4);
  int* bsums   = (int*)alloc((size_t)256 * 4);
  int* ssrc    = (int*)alloc((size_t)T_STEPS * SEG * 4);

  // weight converts
  conv_transpose_wgat<<<dim3((KC * F_INC + 255) / 256), 256, 0, stream>>>(W_gat, wgatT);
  convert_weights<<<dim3(72), 256, 0, stream>>>(W_ih, W_hh, W_att_in, W_att_out,
                                                wihb, whhb, winb, woutb);

  // batched edge sort (flat 3-phase scan)
  hipMemsetAsync(counts, 0, (size_t)2 * TN * 4, stream);
  count_kernel<<<dim3(N_EDGES / 256, T_STEPS), 256, 0, stream>>>(graph, counts);
  scanA<<<dim3(SCAN_BLKS), 1024, 0, stream>>>(counts, offs, bsums);
  scanB<<<dim3(1), 64, 0, stream>>>(bsums, offs);
  scanC<<<dim3(SCAN_BLKS), 1024, 0, stream>>>(offs, bsums);
  scatter_kernel<<<dim3((SEG + 255) / 256, T_STEPS), 256, 0, stream>>>(graph, offs, cursor, ssrc);

  // xw = fts(fp32) @ W_gat^T for ALL t (convert fused) + fused a_src/a_dst
  gemm_bf16<1, 1, 1><<<dim3(KC / 128, (int)(NT / 128)), 256, 0, stream>>>(
      fts, wgatT, nullptr, xw, (int)NT, F_INC, KC, 1, att_src, att_dst, asrc, adst);

  // batched aggregate -> y for ALL t
  aggregate_kernel<<<dim3(N_NODES / 4, T_STEPS), 256, 0, stream>>>(
      xw, asrc, adst, b_gat, offs, ssrc, yall);

  // gi = y @ W_ih^T + b_ih for ALL t (fat parallel GEMM)
  gemm_bf16<1, 0, 0><<<dim3(G3 / 128, (int)(NT / 128)), 256, 0, stream>>>(
      yall, wihb, b_ih, giall, (int)NT, GHD, G3, 1, nullptr, nullptr, nullptr, nullptr);

  // GRU recurrence (gh + combine, one kernel, 32 KB LDS)
  gru_seq<<<dim3(N_NODES / 32), 256, 0, stream>>>(whhb, b_hh, giall, ctx);

  // temporal attention tail
  gemm_bf16<0, 0, 0><<<dim3(1, (N_NODES + 127) / 128), 256, 0, stream>>>(
      ctx + (size_t)(T_STEPS - 1) * N_NODES * GHD, winb, nullptr, qf,
      N_NODES, GHD, GHD, 0, nullptr, nullptr, nullptr, nullptr);
  attn_mid<<<dim3(N_NODES / 4), 256, 0, stream>>>(ctx, qf, comb);
  // out-GEMM with fused classifier + log_softmax (writes d_out directly)
  gemm_bf16<0, 2, 0><<<dim3(1, (N_NODES + 127) / 128), 256, 0, stream>>>(
      comb, woutb, b_cls, nullptr, N_NODES, 2 * GHD, GHD, 0,
      W_cls, W_cls + GHD, out, nullptr);
}

// Round 11
// 712.808 us; speedup vs baseline: 1.0459x; 1.0165x over previous
//
#include <hip/hip_runtime.h>
#include <hip/hip_bf16.h>
#include <math.h>

#define N_NODES 20000
#define N_EDGES 160000
#define T_STEPS 8
#define F_INC   256
#define HEADS   4
#define CCH     128
#define KC      512   // HEADS*CCH
#define GHD     128
#define G3      384
#define SLOPE   0.2f
#define SEG     (N_EDGES + N_NODES)   // edges + self loops per t
#define TN      (T_STEPS * N_NODES)   // 160000
#define SCAN_BLKS ((TN + 1023) / 1024)  // 157

typedef unsigned short u16;
typedef __attribute__((ext_vector_type(8))) short bf16x8;
typedef __attribute__((ext_vector_type(4))) float f32x4;
typedef __attribute__((ext_vector_type(2))) float f32x2;

__device__ __forceinline__ float leakyf(float x) { return x > 0.f ? x : SLOPE * x; }
__device__ __forceinline__ float b2f(u16 u) {
  union { unsigned int i; float f; } x; x.i = ((unsigned int)u) << 16; return x.f;
}
__device__ __forceinline__ u16 f2b(float f) {
  union { float f; unsigned int i; } u; u.f = f;
  unsigned int r = u.i + 0x7FFFu + ((u.i >> 16) & 1u);
  return (u16)(r >> 16);
}
__device__ __forceinline__ float sigf(float x) { return 1.f / (1.f + expf(-x)); }

// async global->LDS 16B (wave-uniform LDS base + lane*16; per-lane global src)
__device__ __forceinline__ void gload16(const void* g, void* l) {
  __builtin_amdgcn_global_load_lds(
      (const __attribute__((address_space(1))) unsigned int*)g,
      (__attribute__((address_space(3))) unsigned int*)l, 16, 0, 0);
}

// pack 8 f32 -> bf16x8 via v_cvt_pk_bf16_f32 (no builtin on gfx950)
__device__ __forceinline__ bf16x8 cvt8(f32x4 lo, f32x4 hi) {
  union { unsigned int u[4]; bf16x8 v; } r;
  asm("v_cvt_pk_bf16_f32 %0, %1, %2" : "=v"(r.u[0]) : "v"(lo[0]), "v"(lo[1]));
  asm("v_cvt_pk_bf16_f32 %0, %1, %2" : "=v"(r.u[1]) : "v"(lo[2]), "v"(lo[3]));
  asm("v_cvt_pk_bf16_f32 %0, %1, %2" : "=v"(r.u[2]) : "v"(hi[0]), "v"(hi[1]));
  asm("v_cvt_pk_bf16_f32 %0, %1, %2" : "=v"(r.u[3]) : "v"(hi[2]), "v"(hi[3]));
  return r.v;
}

// ---------------------------------------------------------------------------
// bf16 MFMA GEMM: C[M,Nt] = A[M,K] @ B^T (+bias). B (Nt,K) bf16.
// AFP32=1: A fp32, converted at fragment-read (v_cvt_pk_bf16_f32).
// FUSE=1: fused a_src/a_dst row-dots (xw gemm).
// FUSE=2: fused classifier: o=leaky(tanh(C)), logits=o@W_cls^T + b_cls,
//         log_softmax -> out (no C write).
// ---------------------------------------------------------------------------
template <int OBF, int FUSE, int AFP32>
__global__ __launch_bounds__(256) void gemm_bf16(
    const void* __restrict__ Ain, const u16* __restrict__ B,
    const float* __restrict__ bias, void* __restrict__ Cout,
    int M, int K, int Nt, int swz,
    const float* __restrict__ attS, const float* __restrict__ attD,
    float* __restrict__ asrc, float* __restrict__ adst)
{
  __shared__ __align__(16) char AsRaw[128 * 32 * 4];
  __shared__ u16 Bs[128][32];
  __shared__ float s_as[128], s_ad[128];
  float* AsF = (float*)AsRaw;
  u16 (*Asb)[32] = (u16(*)[32])AsRaw;
  const int tid  = threadIdx.x;
  const int wave = tid >> 6, lane = tid & 63;
  const int wr = (wave >> 1) * 64, wc = (wave & 1) * 64;
  int bx = blockIdx.x, by = blockIdx.y;
  if (swz) {
    const int gx = gridDim.x;
    const int nwg = gx * (int)gridDim.y;
    const int lin = by * gx + bx;
    const int q = nwg >> 3, r = nwg & 7;
    const int xcd = lin & 7, idx = lin >> 3;
    const int wg = (xcd < r ? xcd * (q + 1) : r * (q + 1) + (xcd - r) * q) + idx;
    bx = wg % gx; by = wg / gx;
  }
  const int bm = by * 128, bn = bx * 128;
  const int l15 = lane & 15, g = lane >> 4;

  if (FUSE && tid < 128) { s_as[tid] = 0.f; s_ad[tid] = 0.f; }

  const int sr = tid >> 2, sd = tid & 3;
  const int ss = sd ^ ((sr >> 1) & 3);
  const u16* aS0 = 0; const u16* aS1 = 0; u16* lA0 = 0; u16* lA1 = 0;
  const float* aF[4]; float* lAF[4];
  if (AFP32) {
    const float* Af = (const float*)Ain;
    const int row0 = tid >> 3, sd8 = tid & 7;
    const int ss8 = sd8 ^ (row0 & 7);
    #pragma unroll
    for (int p = 0; p < 4; ++p) {
      int row = row0 + p * 32;
      aF[p] = Af + (size_t)min(bm + row, M - 1) * K + ss8 * 4;
      lAF[p] = AsF + (size_t)(p * 256 + (tid & ~63)) * 4;
    }
  } else {
    const u16* Ab = (const u16*)Ain;
    aS0 = Ab + (size_t)min(bm + sr,      M - 1) * K + ss * 8;
    aS1 = Ab + (size_t)min(bm + 64 + sr, M - 1) * K + ss * 8;
    lA0 = (u16*)AsRaw + (size_t)(tid & ~63) * 8;
    lA1 = lA0 + 2048;
  }
  const u16* bS0 = B + (size_t)(bn + sr)      * K + ss * 8;
  const u16* bS1 = B + (size_t)(bn + 64 + sr) * K + ss * 8;
  u16* lB0 = &Bs[0][0] + (size_t)(tid & ~63) * 8;
  u16* lB1 = lB0 + 2048;

  f32x4 acc[4][4];
  #pragma unroll
  for (int m = 0; m < 4; ++m)
    #pragma unroll
    for (int n = 0; n < 4; ++n)
      #pragma unroll
      for (int j = 0; j < 4; ++j) acc[m][n][j] = 0.f;

  const int nK = K >> 5;
  for (int kt = 0; kt < nK; ++kt) {
    const int ko = kt * 32;
    if (AFP32) {
      #pragma unroll
      for (int p = 0; p < 4; ++p) gload16(aF[p] + ko, lAF[p]);
    } else {
      gload16(aS0 + ko, lA0);
      gload16(aS1 + ko, lA1);
    }
    gload16(bS0 + ko, lB0);
    gload16(bS1 + ko, lB1);
    __syncthreads();
    bf16x8 af[4], bfr[4];
    #pragma unroll
    for (int m = 0; m < 4; ++m) {
      int row = wr + m * 16 + l15;
      if (AFP32) {
        int s0 = (2 * g) ^ (row & 7), s1 = (2 * g + 1) ^ (row & 7);
        f32x4 lo = *(const f32x4*)&AsF[row * 32 + s0 * 4];
        f32x4 hi = *(const f32x4*)&AsF[row * 32 + s1 * 4];
        af[m] = cvt8(lo, hi);
      } else {
        af[m] = *(const bf16x8*)&Asb[row][(g ^ ((row >> 1) & 3)) * 8];
      }
      int rowb = wc + m * 16 + l15;
      bfr[m] = *(const bf16x8*)&Bs[rowb][(g ^ ((rowb >> 1) & 3)) * 8];
    }
    #pragma unroll
    for (int m = 0; m < 4; ++m)
      #pragma unroll
      for (int n = 0; n < 4; ++n)
        acc[m][n] = __builtin_amdgcn_mfma_f32_16x16x32_bf16(af[m], bfr[n], acc[m][n], 0, 0, 0);
    __syncthreads();
  }
  if (FUSE != 2) {
    #pragma unroll
    for (int m = 0; m < 4; ++m) {
      int row0 = bm + wr + m * 16 + g * 4;
      #pragma unroll
      for (int n = 0; n < 4; ++n) {
        int col = bn + wc + n * 16 + l15;
        float bv = bias ? bias[col] : 0.f;
        #pragma unroll
        for (int j = 0; j < 4; ++j) {
          int row = row0 + j;
          if (row < M) {
            float v = acc[m][n][j] + bv;
            if (OBF) ((u16*)Cout)[(size_t)row * Nt + col] = f2b(v);
            else     ((float*)Cout)[(size_t)row * Nt + col] = v;
          }
        }
      }
    }
  }
  if (FUSE) {
    float ps[4][4], pd[4][4];
    #pragma unroll
    for (int m = 0; m < 4; ++m)
      #pragma unroll
      for (int j = 0; j < 4; ++j) { ps[m][j] = 0.f; pd[m][j] = 0.f; }
    #pragma unroll
    for (int n = 0; n < 4; ++n) {
      int cl = wc + n * 16 + l15;
      float wsv = attS[bn + cl], wdv = attD[bn + cl];
      #pragma unroll
      for (int m = 0; m < 4; ++m)
        #pragma unroll
        for (int j = 0; j < 4; ++j) {
          float av = acc[m][n][j];
          if (FUSE == 2) av = leakyf(tanhf(av));
          ps[m][j] = fmaf(av, wsv, ps[m][j]);
          pd[m][j] = fmaf(av, wdv, pd[m][j]);
        }
    }
    #pragma unroll
    for (int m = 0; m < 4; ++m)
      #pragma unroll
      for (int j = 0; j < 4; ++j)
        #pragma unroll
        for (int msk = 8; msk >= 1; msk >>= 1) {
          ps[m][j] += __shfl_xor(ps[m][j], msk);
          pd[m][j] += __shfl_xor(pd[m][j], msk);
        }
    if (l15 == 0) {
      #pragma unroll
      for (int m = 0; m < 4; ++m)
        #pragma unroll
        for (int j = 0; j < 4; ++j) {
          atomicAdd(&s_as[wr + m * 16 + g * 4 + j], ps[m][j]);
          atomicAdd(&s_ad[wr + m * 16 + g * 4 + j], pd[m][j]);
        }
    }
    __syncthreads();
    if (tid < 128) {
      int row = bm + tid;
      if (row < M) {
        if (FUSE == 1) {
          int h = bn >> 7;
          asrc[(size_t)row * 4 + h] = s_as[tid];
          adst[(size_t)row * 4 + h] = s_ad[tid];
        } else {
          float l0 = s_as[tid] + bias[0];
          float l1 = s_ad[tid] + bias[1];
          float mx = fmaxf(l0, l1);
          float lse = mx + logf(expf(l0 - mx) + expf(l1 - mx));
          asrc[(size_t)row * 2 + 0] = l0 - lse;
          asrc[(size_t)row * 2 + 1] = l1 - lse;
        }
      }
    }
  }
}

// ---------------------------------------------------------------------------
// Merged weight converts: wgat transpose (512 blocks) + 4 small weights (72)
// ---------------------------------------------------------------------------
__global__ void convert_all(const float* __restrict__ w_gat,
                            const float* __restrict__ w_ih, const float* __restrict__ w_hh,
                            const float* __restrict__ w_in, const float* __restrict__ w_out,
                            u16* __restrict__ wgatT,
                            u16* __restrict__ wihb, u16* __restrict__ whhb,
                            u16* __restrict__ winb, u16* __restrict__ woutb)
{
  int b = blockIdx.x;
  if (b < 512) {
    int idx = b * 256 + threadIdx.x;       // KC*F_INC = 131072
    int n = idx >> 8, k = idx & 255;
    wgatT[(size_t)n * F_INC + k] = f2b(w_gat[(size_t)k * KC + n]);
    return;
  }
  int i = (b - 512) * 256 + threadIdx.x;   // 18432 threads
  const float* src; u16* dst; int base;
  if      (i < 6144)  { src = w_ih;  dst = wihb;  base = i; }
  else if (i < 12288) { src = w_hh;  dst = whhb;  base = i - 6144; }
  else if (i < 14336) { src = w_in;  dst = winb;  base = i - 12288; }
  else                { src = w_out; dst = woutb; base = i - 14336; }
  int o = base * 8;
  float4 v0 = *(const float4*)(src + o);
  float4 v1 = *(const float4*)(src + o + 4);
  bf16x8 ov;
  ov[0] = (short)f2b(v0.x); ov[1] = (short)f2b(v0.y);
  ov[2] = (short)f2b(v0.z); ov[3] = (short)f2b(v0.w);
  ov[4] = (short)f2b(v1.x); ov[5] = (short)f2b(v1.y);
  ov[6] = (short)f2b(v1.z); ov[7] = (short)f2b(v1.w);
  *(bf16x8*)(dst + o) = ov;
}

// ---------------------------------------------------------------------------
// Batched edge counting-sort (all T at once). offs = FLAT global scan of
// (counts+1) over all T*N nodes; per-t bases (t*SEG) emerge automatically.
// ---------------------------------------------------------------------------
__global__ void count_kernel(const int* __restrict__ graph, int* __restrict__ counts) {
  int e = blockIdx.x * 256 + threadIdx.x;
  int t = blockIdx.y;
  if (e < N_EDGES) {
    int d = graph[(size_t)t * 2 * N_EDGES + N_EDGES + e];
    atomicAdd(&counts[t * N_NODES + d], 1);
  }
}

__global__ __launch_bounds__(1024) void scanA(
    const int* __restrict__ counts, int* __restrict__ offs, int* __restrict__ bsums)
{
  const int tid = threadIdx.x, lane = tid & 63, w = tid >> 6;
  __shared__ int s_wt[16];
  int i = blockIdx.x * 1024 + tid;
  int v = (i < TN) ? (counts[i] + 1) : 0;   // +1 self loop
  int x = v;
  #pragma unroll
  for (int d = 1; d < 64; d <<= 1) {
    int nvl = __shfl_up(x, d, 64);
    if (lane >= d) x += nvl;
  }
  if (lane == 63) s_wt[w] = x;
  __syncthreads();
  if (tid < 16) {
    int y = s_wt[tid];
    #pragma unroll
    for (int d = 1; d < 16; d <<= 1) {
      int nvl = __shfl_up(y, d, 64);
      if (tid >= d) y += nvl;
    }
    s_wt[tid] = y;
  }
  __syncthreads();
  int wbase = (w > 0) ? s_wt[w - 1] : 0;
  if (i < TN) offs[i] = wbase + x - v;       // block-local exclusive
  if (tid == 1023) bsums[blockIdx.x] = s_wt[15];
}

__global__ void scanB(int* __restrict__ bsums, int* __restrict__ offs) {
  const int lane = threadIdx.x;  // 64 threads, 1 block
  int carry = 0;
  for (int base = 0; base < 192; base += 64) {
    int idx = base + lane;
    int v = (idx < SCAN_BLKS) ? bsums[idx] : 0;
    int x = v;
    #pragma unroll
    for (int d = 1; d < 64; d <<= 1) {
      int nvl = __shfl_up(x, d, 64);
      if (lane >= d) x += nvl;
    }
    if (idx < SCAN_BLKS) bsums[idx] = carry + x - v;   // exclusive
    carry += __shfl(x, 63);
  }
  if (lane == 0) offs[TN] = carry;   // == T_STEPS * SEG
}

__global__ __launch_bounds__(1024) void scanC(int* __restrict__ offs, const int* __restrict__ bsums) {
  int i = blockIdx.x * 1024 + threadIdx.x;
  if (i < TN) offs[i] += bsums[blockIdx.x];
}

__global__ void scatter_kernel(const int* __restrict__ graph, const int* __restrict__ offs,
                               int* __restrict__ cursor, int* __restrict__ ssrc)
{
  int i = blockIdx.x * 256 + threadIdx.x;
  int t = blockIdx.y;
  if (i >= SEG) return;
  int s, d;
  if (i < N_EDGES) {
    s = graph[(size_t)t * 2 * N_EDGES + i];
    d = graph[(size_t)t * 2 * N_EDGES + N_EDGES + i];
  } else {
    s = d = i - N_EDGES;
  }
  int pos = offs[t * N_NODES + d] + atomicAdd(&cursor[t * N_NODES + d], 1);
  ssrc[pos] = s;
}

// ---------------------------------------------------------------------------
// Batched aggregate: head-interleaved online softmax + branch-free padded
// 8-wide gather. Accumulators as f32x2 so accumulate/rescale emit
// v_pk_fma_f32 / v_pk_mul_f32 (half the VALU insts in the hot loop).
// ---------------------------------------------------------------------------
__global__ __launch_bounds__(256) void aggregate_kernel(
    const u16* __restrict__ xw, const float* __restrict__ a_src,
    const float* __restrict__ a_dst, const float* __restrict__ b_gat,
    const int* __restrict__ offs, const int* __restrict__ ssrc,
    u16* __restrict__ yout)
{
  const int wv = threadIdx.x >> 6, lane = threadIdx.x & 63;
  const int nd = blockIdx.x * 4 + wv;
  const int t  = blockIdx.y;
  const int ob = t * N_NODES + nd;
  const int beg = offs[ob], end = offs[ob + 1];
  const size_t rowbase = (size_t)t * N_NODES;
  const int he   = lane & 3;
  const int eidx = lane >> 2;
  const int hl   = lane >> 4;
  const float advh = a_dst[(rowbase + nd) * 4 + he];

  float m = -INFINITY, ssum = 0.f;
  f32x2 acc2[4];
  #pragma unroll
  for (int j = 0; j < 4; ++j) { acc2[j][0] = 0.f; acc2[j][1] = 0.f; }

#define FMA8(W, X)                                                        \
    { f32x2 _w2; _w2[0] = (W); _w2[1] = _w2[0];                           \
      f32x2 _v;                                                           \
      _v[0] = __uint_as_float((unsigned)(X).x << 16);                     \
      _v[1] = __uint_as_float((unsigned)(X).x & 0xffff0000u);             \
      acc2[0] += _w2 * _v;                                                \
      _v[0] = __uint_as_float((unsigned)(X).y << 16);                     \
      _v[1] = __uint_as_float((unsigned)(X).y & 0xffff0000u);             \
      acc2[1] += _w2 * _v;                                                \
      _v[0] = __uint_as_float((unsigned)(X).z << 16);                     \
      _v[1] = __uint_as_float((unsigned)(X).z & 0xffff0000u);             \
      acc2[2] += _w2 * _v;                                                \
      _v[0] = __uint_as_float((unsigned)(X).w << 16);                     \
      _v[1] = __uint_as_float((unsigned)(X).w & 0xffff0000u);             \
      acc2[3] += _w2 * _v; }
#define LDE(SVAR) (*(const int4*)&xw[(rowbase + (SVAR)) * KC + lane * 8])

  for (int base = beg; base < end; base += 16) {
    const int cnt = min(16, end - base);
    const int e = base + eidx;
    const int sidx = (e < end) ? ssrc[e] : ssrc[base];
    const float av = a_src[(rowbase + sidx) * 4 + he];
    const float a = (eidx < cnt) ? leakyf(av + advh) : -INFINITY;
    float cm = a;
    cm = fmaxf(cm, __shfl_xor(cm, 4));
    cm = fmaxf(cm, __shfl_xor(cm, 8));
    cm = fmaxf(cm, __shfl_xor(cm, 16));
    cm = fmaxf(cm, __shfl_xor(cm, 32));
    const float nm = fmaxf(m, cm);
    const float sc = expf(m - nm);
    const float w = expf(a - nm);
    float ts = w;
    ts += __shfl_xor(ts, 4);
    ts += __shfl_xor(ts, 8);
    ts += __shfl_xor(ts, 16);
    ts += __shfl_xor(ts, 32);
    ssum = ssum * sc + ts;
    m = nm;
    {
      const float schl = __shfl(sc, hl);
      f32x2 sc2; sc2[0] = schl; sc2[1] = schl;
      #pragma unroll
      for (int j = 0; j < 4; ++j) acc2[j] *= sc2;
    }

    const int cpad = (cnt + 3) & ~3;
    int b4 = 0;
    for (; b4 + 8 <= cpad; b4 += 8) {
      const int s0 = __shfl(sidx, (b4 + 0) << 2);
      const int s1 = __shfl(sidx, (b4 + 1) << 2);
      const int s2 = __shfl(sidx, (b4 + 2) << 2);
      const int s3 = __shfl(sidx, (b4 + 3) << 2);
      const int s4 = __shfl(sidx, (b4 + 4) << 2);
      const int s5 = __shfl(sidx, (b4 + 5) << 2);
      const int s6 = __shfl(sidx, (b4 + 6) << 2);
      const int s7 = __shfl(sidx, (b4 + 7) << 2);
      const int4 x0 = LDE(s0); const int4 x1 = LDE(s1);
      const int4 x2 = LDE(s2); const int4 x3 = LDE(s3);
      const int4 x4 = LDE(s4); const int4 x5 = LDE(s5);
      const int4 x6 = LDE(s6); const int4 x7 = LDE(s7);
      const float w0 = __shfl(w, ((b4 + 0) << 2) + hl);
      const float w1 = __shfl(w, ((b4 + 1) << 2) + hl);
      const float w2 = __shfl(w, ((b4 + 2) << 2) + hl);
      const float w3 = __shfl(w, ((b4 + 3) << 2) + hl);
      const float w4 = __shfl(w, ((b4 + 4) << 2) + hl);
      const float w5 = __shfl(w, ((b4 + 5) << 2) + hl);
      const float w6 = __shfl(w, ((b4 + 6) << 2) + hl);
      const float w7 = __shfl(w, ((b4 + 7) << 2) + hl);
      FMA8(w0, x0); FMA8(w1, x1); FMA8(w2, x2); FMA8(w3, x3);
      FMA8(w4, x4); FMA8(w5, x5); FMA8(w6, x6); FMA8(w7, x7);
    }
    if (b4 < cpad) {
      const int s0 = __shfl(sidx, (b4 + 0) << 2);
      const int s1 = __shfl(sidx, (b4 + 1) << 2);
      const int s2 = __shfl(sidx, (b4 + 2) << 2);
      const int s3 = __shfl(sidx, (b4 + 3) << 2);
      const int4 x0 = LDE(s0); const int4 x1 = LDE(s1);
      const int4 x2 = LDE(s2); const int4 x3 = LDE(s3);
      const float w0 = __shfl(w, ((b4 + 0) << 2) + hl);
      const float w1 = __shfl(w, ((b4 + 1) << 2) + hl);
      const float w2 = __shfl(w, ((b4 + 2) << 2) + hl);
      const float w3 = __shfl(w, ((b4 + 3) << 2) + hl);
      FMA8(w0, x0); FMA8(w1, x1); FMA8(w2, x2); FMA8(w3, x3);
    }
  }
#undef LDE
#undef FMA8

  const float sh = __shfl(ssum, hl);
  const float inv = 1.f / (sh + 1e-16f);
  float acc[8];
  #pragma unroll
  for (int k = 0; k < 8; ++k) {
    acc[k] = acc2[k >> 1][k & 1] * inv;
    acc[k] += __shfl_xor(acc[k], 16);
    acc[k] += __shfl_xor(acc[k], 32);
  }
  if (lane < 16) {
    bf16x8 ov;
    #pragma unroll
    for (int k = 0; k < 8; ++k) {
      float v = acc[k] * 0.25f + b_gat[lane * 8 + k];
      ov[k] = (short)f2b(leakyf(v));
    }
    *(bf16x8*)&yout[(rowbase + nd) * GHD + lane * 8] = ov;
  }
}

// ---------------------------------------------------------------------------
// Fused GRU recurrence + q-projection. 625 blocks x 32 rows. gh-GEMM per
// step; h fp32 in regs + bf16 in swizzled LDS hA; W_hh per-kt via
// global_load_lds; gh restaged through LDS. After t=7: q = h @ W_in^T via
// the same machinery (W_in slices into reg2's first 8 KB), q written bf16.
// ---------------------------------------------------------------------------
__global__ __launch_bounds__(256) void gru_seq(
    const u16* __restrict__ Whh, const u16* __restrict__ Win,
    const float* __restrict__ b_hh, const u16* __restrict__ giall,
    u16* __restrict__ ctx, u16* __restrict__ qb)
{
  __shared__ u16 hA[32][128];       // 8 KB: h bf16, slot^=(row&7) swizzle
  __shared__ u16 reg2[12288];       // 24 KB: Bs (384x32) during MFMA, gh after
  u16 (*Bs)[32] = (u16(*)[32])reg2;
  const int tid = threadIdx.x, lane = tid & 63, wv = tid >> 6;
  const int l15 = lane & 15, g = lane >> 4;
  const int bm = blockIdx.x * 32;   // 20000 = 625*32, no tail

  const int sr = tid >> 2, sd = tid & 3;
  const int ssb = sd ^ ((sr >> 1) & 3);
  const u16* bS[6]; u16* lB[6];
  #pragma unroll
  for (int p = 0; p < 6; ++p) {
    bS[p] = Whh + (size_t)(sr + p * 64) * GHD + ssb * 8;
    lB[p] = reg2 + (size_t)(p * 256 + (tid & ~63)) * 8;
  }
  float bbv[6];
  #pragma unroll
  for (int n = 0; n < 6; ++n) bbv[n] = b_hh[wv * 96 + n * 16 + l15];

  const int cr = tid >> 3;
  const int cg = (tid & 7) * 8;
  const int grow = bm + cr;
  const size_t gb = (size_t)grow * G3;
  const size_t cb = (size_t)grow * GHD;
  float hp[2][8];

  // ---- t = 0: h = (1-z)*tanh(i_n + r*b_hh_n), gh == b_hh ----
  #pragma unroll
  for (int q = 0; q < 2; ++q) {
    const int c0 = cg + q * 64;
    bf16x8 ir8 = *(const bf16x8*)&giall[gb + c0];
    bf16x8 iz8 = *(const bf16x8*)&giall[gb + 128 + c0];
    bf16x8 in8 = *(const bf16x8*)&giall[gb + 256 + c0];
    float4 br0 = *(const float4*)&b_hh[c0];       float4 br1 = *(const float4*)&b_hh[c0 + 4];
    float4 bz0 = *(const float4*)&b_hh[128 + c0]; float4 bz1 = *(const float4*)&b_hh[128 + c0 + 4];
    float4 bn0 = *(const float4*)&b_hh[256 + c0]; float4 bn1 = *(const float4*)&b_hh[256 + c0 + 4];
    float bhr[8] = {br0.x, br0.y, br0.z, br0.w, br1.x, br1.y, br1.z, br1.w};
    float bhz[8] = {bz0.x, bz0.y, bz0.z, bz0.w, bz1.x, bz1.y, bz1.z, bz1.w};
    float bhn[8] = {bn0.x, bn0.y, bn0.z, bn0.w, bn1.x, bn1.y, bn1.z, bn1.w};
    bf16x8 hv;
    #pragma unroll
    for (int k = 0; k < 8; ++k) {
      float rr = sigf(b2f((u16)ir8[k]) + bhr[k]);
      float zz = sigf(b2f((u16)iz8[k]) + bhz[k]);
      float nn = tanhf(b2f((u16)in8[k]) + rr * bhn[k]);
      float h = (1.f - zz) * nn;
      hp[q][k] = h;
      hv[k] = (short)f2b(h);
    }
    const int sl = (c0 >> 3) ^ (cr & 7);
    *(bf16x8*)&hA[cr][sl * 8] = hv;
    *(bf16x8*)&ctx[cb + c0] = hv;
  }
  __syncthreads();

  // ---- t = 1..7 ----
  for (int t = 1; t < T_STEPS; ++t) {
    const u16* gi_t = giall + (size_t)t * N_NODES * G3;
    u16* ctx_t = ctx + (size_t)t * N_NODES * GHD;
    f32x4 acc[2][6];
    #pragma unroll
    for (int m = 0; m < 2; ++m)
      #pragma unroll
      for (int n = 0; n < 6; ++n)
        #pragma unroll
        for (int j = 0; j < 4; ++j) acc[m][n][j] = 0.f;

    #pragma unroll
    for (int kt = 0; kt < 4; ++kt) {
      const int ko = kt * 32;
      #pragma unroll
      for (int p = 0; p < 6; ++p) gload16(bS[p] + ko, lB[p]);
      __syncthreads();
      bf16x8 af[2], bfr[6];
      #pragma unroll
      for (int m = 0; m < 2; ++m) {
        int row = m * 16 + l15;
        int sl = (kt * 4 + g) ^ (row & 7);
        af[m] = *(const bf16x8*)&hA[row][sl * 8];
      }
      #pragma unroll
      for (int n = 0; n < 6; ++n) {
        int rowb = wv * 96 + n * 16 + l15;
        bfr[n] = *(const bf16x8*)&Bs[rowb][(g ^ ((rowb >> 1) & 3)) * 8];
      }
      #pragma unroll
      for (int m = 0; m < 2; ++m)
        #pragma unroll
        for (int n = 0; n < 6; ++n)
          acc[m][n] = __builtin_amdgcn_mfma_f32_16x16x32_bf16(af[m], bfr[n], acc[m][n], 0, 0, 0);
      __syncthreads();
    }
    // stage gh (+b_hh) into reg2 (clobbers Bs; all reads done)
    #pragma unroll
    for (int m = 0; m < 2; ++m)
      #pragma unroll
      for (int n = 0; n < 6; ++n) {
        int c = wv * 96 + n * 16 + l15;
        #pragma unroll
        for (int j = 0; j < 4; ++j) {
          int r = m * 16 + g * 4 + j;
          reg2[r * 384 + (((c >> 3) ^ (r & 7)) << 3) + (c & 7)] = f2b(acc[m][n][j] + bbv[n]);
        }
      }
    __syncthreads();
    // combine (reads reg2, writes hA + ctx; hp carries fp32 state)
    #pragma unroll
    for (int q = 0; q < 2; ++q) {
      const int c0 = cg + q * 64;
      const int sl0 = ((c0 >> 3) ^ (cr & 7));
      const int sl1 = (((128 + c0) >> 3) ^ (cr & 7));
      const int sl2 = (((256 + c0) >> 3) ^ (cr & 7));
      bf16x8 hr8 = *(bf16x8*)&reg2[cr * 384 + sl0 * 8];
      bf16x8 hz8 = *(bf16x8*)&reg2[cr * 384 + sl1 * 8];
      bf16x8 hn8 = *(bf16x8*)&reg2[cr * 384 + sl2 * 8];
      bf16x8 ir8 = *(const bf16x8*)&gi_t[gb + c0];
      bf16x8 iz8 = *(const bf16x8*)&gi_t[gb + 128 + c0];
      bf16x8 in8 = *(const bf16x8*)&gi_t[gb + 256 + c0];
      bf16x8 hv;
      #pragma unroll
      for (int k = 0; k < 8; ++k) {
        float rr = sigf(b2f((u16)ir8[k]) + b2f((u16)hr8[k]));
        float zz = sigf(b2f((u16)iz8[k]) + b2f((u16)hz8[k]));
        float nn = tanhf(b2f((u16)in8[k]) + rr * b2f((u16)hn8[k]));
        float h = (1.f - zz) * nn + zz * hp[q][k];
        hp[q][k] = h;
        hv[k] = (short)f2b(h);
      }
      const int slh = (c0 >> 3) ^ (cr & 7);
      *(bf16x8*)&hA[cr][slh * 8] = hv;
      *(bf16x8*)&ctx_t[cb + c0] = hv;
    }
    __syncthreads();
  }

  // ---- q = h_final @ W_in^T (32x128 @ (128,128)^T), same machinery ----
  {
    const u16* qS[2]; u16* lQ[2];
    #pragma unroll
    for (int p = 0; p < 2; ++p) {
      qS[p] = Win + (size_t)(sr + p * 64) * GHD + ssb * 8;
      lQ[p] = reg2 + (size_t)(p * 256 + (tid & ~63)) * 8;
    }
    f32x4 accq[2][2];
    #pragma unroll
    for (int m = 0; m < 2; ++m)
      #pragma unroll
      for (int n = 0; n < 2; ++n)
        #pragma unroll
        for (int j = 0; j < 4; ++j) accq[m][n][j] = 0.f;

    #pragma unroll
    for (int kt = 0; kt < 4; ++kt) {
      const int ko = kt * 32;
      #pragma unroll
      for (int p = 0; p < 2; ++p) gload16(qS[p] + ko, lQ[p]);
      __syncthreads();
      bf16x8 af[2], bq[2];
      #pragma unroll
      for (int m = 0; m < 2; ++m) {
        int row = m * 16 + l15;
        int sl = (kt * 4 + g) ^ (row & 7);
        af[m] = *(const bf16x8*)&hA[row][sl * 8];
      }
      #pragma unroll
      for (int n = 0; n < 2; ++n) {
        int rowb = wv * 32 + n * 16 + l15;     // 0..127
        bq[n] = *(const bf16x8*)&Bs[rowb][(g ^ ((rowb >> 1) & 3)) * 8];
      }
      #pragma unroll
      for (int m = 0; m < 2; ++m)
        #pragma unroll
        for (int n = 0; n < 2; ++n)
          accq[m][n] = __builtin_amdgcn_mfma_f32_16x16x32_bf16(af[m], bq[n], accq[m][n], 0, 0, 0);
      __syncthreads();
    }
    #pragma unroll
    for (int m = 0; m < 2; ++m) {
      int row0 = bm + m * 16 + g * 4;
      #pragma unroll
      for (int n = 0; n < 2; ++n) {
        int col = wv * 32 + n * 16 + l15;
        #pragma unroll
        for (int j = 0; j < 4; ++j)
          qb[(size_t)(row0 + j) * GHD + col] = f2b(accq[m][n][j]);
      }
    }
  }
}

// ---------------------------------------------------------------------------
// Temporal attention middle: scores + softmax + mix. One wave / node.
// q is bf16 now (produced by gru_seq).
// ---------------------------------------------------------------------------
__global__ __launch_bounds__(256) void attn_mid(
    const u16* __restrict__ ctx, const u16* __restrict__ qb,
    u16* __restrict__ comb)
{
  const int node = blockIdx.x * 4 + (threadIdx.x >> 6);
  const int lane = threadIdx.x & 63;
  if (node >= N_NODES) return;
  const float q0 = b2f(qb[(size_t)node * GHD + lane]);
  const float q1 = b2f(qb[(size_t)node * GHD + 64 + lane]);
  float c0[T_STEPS], c1[T_STEPS], w[T_STEPS];
  float mx = -1e30f;
  #pragma unroll
  for (int t = 0; t < T_STEPS; ++t) {
    const u16* cr = ctx + ((size_t)t * N_NODES + node) * GHD;
    c0[t] = b2f(cr[lane]); c1[t] = b2f(cr[64 + lane]);
    float p = q0 * c0[t] + q1 * c1[t];
    #pragma unroll
    for (int m = 32; m >= 1; m >>= 1) p += __shfl_xor(p, m);
    w[t] = p;
    mx = fmaxf(mx, p);
  }
  float s = 0.f;
  #pragma unroll
  for (int t = 0; t < T_STEPS; ++t) { w[t] = expf(w[t] - mx); s += w[t]; }
  const float inv = 1.f / s;
  float m0 = 0.f, m1 = 0.f;
  #pragma unroll
  for (int t = 0; t < T_STEPS; ++t) { m0 = fmaf(w[t], c0[t], m0); m1 = fmaf(w[t], c1[t], m1); }
  m0 *= inv; m1 *= inv;
  u16* cb = comb + (size_t)node * 2 * GHD;
  cb[lane]       = f2b(m0);
  cb[64 + lane]  = f2b(m1);
  cb[128 + lane] = qb[(size_t)node * GHD + lane];
  cb[192 + lane] = qb[(size_t)node * GHD + 64 + lane];
}

// ---------------------------------------------------------------------------
extern "C" void kernel_launch(void* const* d_in, const int* in_sizes, int n_in,
                              void* d_out, int out_size, void* d_ws, size_t ws_size,
                              hipStream_t stream)
{
  const int*   graph     = (const int*)  d_in[0];
  const float* fts       = (const float*)d_in[1];
  const float* W_gat     = (const float*)d_in[3];
  const float* att_src   = (const float*)d_in[4];
  const float* att_dst   = (const float*)d_in[5];
  const float* b_gat     = (const float*)d_in[6];
  const float* W_ih      = (const float*)d_in[7];
  const float* W_hh      = (const float*)d_in[8];
  const float* b_ih      = (const float*)d_in[9];
  const float* b_hh      = (const float*)d_in[10];
  const float* W_att_in  = (const float*)d_in[11];
  const float* W_att_out = (const float*)d_in[12];
  const float* W_cls     = (const float*)d_in[13];
  const float* b_cls     = (const float*)d_in[14];
  float* out = (float*)d_out;

  char* ws = (char*)d_ws;
  size_t off = 0;
  auto alloc = [&](size_t bytes) {
    void* p = ws + off;
    off = (off + bytes + 255) & ~(size_t)255;
    return p;
  };
  const size_t NT = (size_t)TN;                    // 160000 rows
  u16*   wgatT = (u16*)alloc((size_t)KC * F_INC * 2);
  u16*   wihb  = (u16*)alloc((size_t)G3 * GHD * 2);
  u16*   whhb  = (u16*)alloc((size_t)G3 * GHD * 2);
  u16*   winb  = (u16*)alloc((size_t)GHD * GHD * 2);
  u16*   woutb = (u16*)alloc((size_t)GHD * 2 * GHD * 2);
  u16*   xw    = (u16*)alloc(NT * KC * 2);          // 164 MB
  float* asrc  = (float*)alloc(NT * 4 * 4);
  float* adst  = (float*)alloc(NT * 4 * 4);
  u16*   yall  = (u16*)alloc(NT * GHD * 2);         // 41 MB
  u16*   giall = (u16*)alloc(NT * G3 * 2);          // 123 MB
  u16*   ctx   = (u16*)alloc(NT * GHD * 2);         // 41 MB
  u16*   qb    = (u16*)alloc((size_t)N_NODES * GHD * 2);
  u16*   comb  = (u16*)alloc((size_t)N_NODES * 2 * GHD * 2);
  int* counts  = (int*)alloc((size_t)2 * TN * 4);   // counts + cursor
  int* cursor  = counts + TN;
  int* offs    = (int*)alloc((size_t)(TN + 1) * 4);
  int* bsums   = (int*)alloc((size_t)256 * 4);
  int* ssrc    = (int*)alloc((size_t)T_STEPS * SEG * 4);

  // merged weight converts (wgat transpose + 4 small weights)
  convert_all<<<dim3(584), 256, 0, stream>>>(W_gat, W_ih, W_hh, W_att_in, W_att_out,
                                             wgatT, wihb, whhb, winb, woutb);

  // batched edge sort (flat 3-phase scan)
  hipMemsetAsync(counts, 0, (size_t)2 * TN * 4, stream);
  count_kernel<<<dim3(N_EDGES / 256, T_STEPS), 256, 0, stream>>>(graph, counts);
  scanA<<<dim3(SCAN_BLKS), 1024, 0, stream>>>(counts, offs, bsums);
  scanB<<<dim3(1), 64, 0, stream>>>(bsums, offs);
  scanC<<<dim3(SCAN_BLKS), 1024, 0, stream>>>(offs, bsums);
  scatter_kernel<<<dim3((SEG + 255) / 256, T_STEPS), 256, 0, stream>>>(graph, offs, cursor, ssrc);

  // xw = fts(fp32) @ W_gat^T for ALL t (convert fused) + fused a_src/a_dst
  gemm_bf16<1, 1, 1><<<dim3(KC / 128, (int)(NT / 128)), 256, 0, stream>>>(
      fts, wgatT, nullptr, xw, (int)NT, F_INC, KC, 1, att_src, att_dst, asrc, adst);

  // batched aggregate -> y for ALL t
  aggregate_kernel<<<dim3(N_NODES / 4, T_STEPS), 256, 0, stream>>>(
      xw, asrc, adst, b_gat, offs, ssrc, yall);

  // gi = y @ W_ih^T + b_ih for ALL t (fat parallel GEMM)
  gemm_bf16<1, 0, 0><<<dim3(G3 / 128, (int)(NT / 128)), 256, 0, stream>>>(
      yall, wihb, b_ih, giall, (int)NT, GHD, G3, 1, nullptr, nullptr, nullptr, nullptr);

  // GRU recurrence + fused q-projection (one kernel, 32 KB LDS)
  gru_seq<<<dim3(N_NODES / 32), 256, 0, stream>>>(whhb, winb, b_hh, giall, ctx, qb);

  // temporal attention tail
  attn_mid<<<dim3(N_NODES / 4), 256, 0, stream>>>(ctx, qb, comb);
  // out-GEMM with fused classifier + log_softmax (writes d_out directly)
  gemm_bf16<0, 2, 0><<<dim3(1, (N_NODES + 127) / 128), 256, 0, stream>>>(
      comb, woutb, b_cls, nullptr, N_NODES, 2 * GHD, GHD, 0,
      W_cls, W_cls + GHD, out, nullptr);
}

// Round 12
// 712.650 us; speedup vs baseline: 1.0462x; 1.0002x over previous
//
#include <hip/hip_runtime.h>
#include <hip/hip_bf16.h>
#include <math.h>

#define N_NODES 20000
#define N_EDGES 160000
#define T_STEPS 8
#define F_INC   256
#define HEADS   4
#define CCH     128
#define KC      512   // HEADS*CCH
#define GHD     128
#define G3      384
#define SLOPE   0.2f
#define SEG     (N_EDGES + N_NODES)   // edges + self loops per t
#define TN      (T_STEPS * N_NODES)   // 160000
#define SCAN_BLKS ((TN + 1023) / 1024)  // 157

typedef unsigned short u16;
typedef __attribute__((ext_vector_type(8))) short bf16x8;
typedef __attribute__((ext_vector_type(4))) float f32x4;
typedef __attribute__((ext_vector_type(2))) float f32x2;

__device__ __forceinline__ float leakyf(float x) { return x > 0.f ? x : SLOPE * x; }
__device__ __forceinline__ float b2f(u16 u) {
  union { unsigned int i; float f; } x; x.i = ((unsigned int)u) << 16; return x.f;
}
__device__ __forceinline__ u16 f2b(float f) {
  union { float f; unsigned int i; } u; u.f = f;
  unsigned int r = u.i + 0x7FFFu + ((u.i >> 16) & 1u);
  return (u16)(r >> 16);
}
__device__ __forceinline__ float sigf(float x) { return 1.f / (1.f + expf(-x)); }

// async global->LDS 16B (wave-uniform LDS base + lane*16; per-lane global src)
__device__ __forceinline__ void gload16(const void* g, void* l) {
  __builtin_amdgcn_global_load_lds(
      (const __attribute__((address_space(1))) unsigned int*)g,
      (__attribute__((address_space(3))) unsigned int*)l, 16, 0, 0);
}

// pack 8 f32 -> bf16x8 via v_cvt_pk_bf16_f32 (no builtin on gfx950)
__device__ __forceinline__ bf16x8 cvt8(float4 lo, float4 hi) {
  union { unsigned int u[4]; bf16x8 v; } r;
  asm("v_cvt_pk_bf16_f32 %0, %1, %2" : "=v"(r.u[0]) : "v"(lo.x), "v"(lo.y));
  asm("v_cvt_pk_bf16_f32 %0, %1, %2" : "=v"(r.u[1]) : "v"(lo.z), "v"(lo.w));
  asm("v_cvt_pk_bf16_f32 %0, %1, %2" : "=v"(r.u[2]) : "v"(hi.x), "v"(hi.y));
  asm("v_cvt_pk_bf16_f32 %0, %1, %2" : "=v"(r.u[3]) : "v"(hi.z), "v"(hi.w));
  return r.v;
}

// ---------------------------------------------------------------------------
// bf16 MFMA GEMM: C[M,Nt] = A[M,K] @ B^T (+bias). B (Nt,K) bf16.
// AFP32=1: A fp32, reg-staged (global->reg, cvt_pk, ds_write_b128 into the
//          SAME conflict-free swizzled bf16 layout the read path expects).
// FUSE=1: fused a_src/a_dst row-dots (xw gemm).
// FUSE=2: fused classifier: o=leaky(tanh(C)), logits=o@W_cls^T + b_cls,
//         log_softmax -> out (no C write).
// ---------------------------------------------------------------------------
template <int OBF, int FUSE, int AFP32>
__global__ __launch_bounds__(256) void gemm_bf16(
    const void* __restrict__ Ain, const u16* __restrict__ B,
    const float* __restrict__ bias, void* __restrict__ Cout,
    int M, int K, int Nt, int swz,
    const float* __restrict__ attS, const float* __restrict__ attD,
    float* __restrict__ asrc, float* __restrict__ adst)
{
  __shared__ u16 Asb[128][32];
  __shared__ u16 Bs[128][32];
  __shared__ float s_as[128], s_ad[128];
  const int tid  = threadIdx.x;
  const int wave = tid >> 6, lane = tid & 63;
  const int wr = (wave >> 1) * 64, wc = (wave & 1) * 64;
  int bx = blockIdx.x, by = blockIdx.y;
  if (swz) {
    const int gx = gridDim.x;
    const int nwg = gx * (int)gridDim.y;
    const int lin = by * gx + bx;
    const int q = nwg >> 3, r = nwg & 7;
    const int xcd = lin & 7, idx = lin >> 3;
    const int wg = (xcd < r ? xcd * (q + 1) : r * (q + 1) + (xcd - r) * q) + idx;
    bx = wg % gx; by = wg / gx;
  }
  const int bm = by * 128, bn = bx * 128;
  const int l15 = lane & 15, g = lane >> 4;

  if (FUSE && tid < 128) { s_as[tid] = 0.f; s_ad[tid] = 0.f; }

  const int sr = tid >> 2, sd = tid & 3;
  const int ss = sd ^ ((sr >> 1) & 3);
  // bf16-A async path
  const u16* aS0 = 0; const u16* aS1 = 0; u16* lA0 = 0; u16* lA1 = 0;
  // fp32-A reg-staged path
  const float* aF0 = 0; const float* aF1 = 0; u16* wA0 = 0; u16* wA1 = 0;
  if (AFP32) {
    const float* Af = (const float*)Ain;
    aF0 = Af + (size_t)min(bm + sr,      M - 1) * K + sd * 8;
    aF1 = Af + (size_t)min(bm + 64 + sr, M - 1) * K + sd * 8;
    wA0 = &Asb[sr][ss * 8];        // swizzled dest slot (read path expects it)
    wA1 = &Asb[sr + 64][ss * 8];   // ((sr+64)>>1)&3 == (sr>>1)&3
  } else {
    const u16* Ab = (const u16*)Ain;
    aS0 = Ab + (size_t)min(bm + sr,      M - 1) * K + ss * 8;
    aS1 = Ab + (size_t)min(bm + 64 + sr, M - 1) * K + ss * 8;
    lA0 = &Asb[0][0] + (size_t)(tid & ~63) * 8;
    lA1 = lA0 + 2048;
  }
  const u16* bS0 = B + (size_t)(bn + sr)      * K + ss * 8;
  const u16* bS1 = B + (size_t)(bn + 64 + sr) * K + ss * 8;
  u16* lB0 = &Bs[0][0] + (size_t)(tid & ~63) * 8;
  u16* lB1 = lB0 + 2048;

  f32x4 acc[4][4];
  #pragma unroll
  for (int m = 0; m < 4; ++m)
    #pragma unroll
    for (int n = 0; n < 4; ++n)
      #pragma unroll
      for (int j = 0; j < 4; ++j) acc[m][n][j] = 0.f;

  const int nK = K >> 5;
  for (int kt = 0; kt < nK; ++kt) {
    const int ko = kt * 32;
    gload16(bS0 + ko, lB0);
    gload16(bS1 + ko, lB1);
    if (AFP32) {
      float4 a0 = *(const float4*)(aF0 + ko);
      float4 a1 = *(const float4*)(aF0 + ko + 4);
      float4 a2 = *(const float4*)(aF1 + ko);
      float4 a3 = *(const float4*)(aF1 + ko + 4);
      *(bf16x8*)wA0 = cvt8(a0, a1);
      *(bf16x8*)wA1 = cvt8(a2, a3);
    } else {
      gload16(aS0 + ko, lA0);
      gload16(aS1 + ko, lA1);
    }
    __syncthreads();
    bf16x8 af[4], bfr[4];
    #pragma unroll
    for (int m = 0; m < 4; ++m) {
      int row = wr + m * 16 + l15;
      af[m] = *(const bf16x8*)&Asb[row][(g ^ ((row >> 1) & 3)) * 8];
      int rowb = wc + m * 16 + l15;
      bfr[m] = *(const bf16x8*)&Bs[rowb][(g ^ ((rowb >> 1) & 3)) * 8];
    }
    #pragma unroll
    for (int m = 0; m < 4; ++m)
      #pragma unroll
      for (int n = 0; n < 4; ++n)
        acc[m][n] = __builtin_amdgcn_mfma_f32_16x16x32_bf16(af[m], bfr[n], acc[m][n], 0, 0, 0);
    __syncthreads();
  }
  if (FUSE != 2) {
    #pragma unroll
    for (int m = 0; m < 4; ++m) {
      int row0 = bm + wr + m * 16 + g * 4;
      #pragma unroll
      for (int n = 0; n < 4; ++n) {
        int col = bn + wc + n * 16 + l15;
        float bv = bias ? bias[col] : 0.f;
        #pragma unroll
        for (int j = 0; j < 4; ++j) {
          int row = row0 + j;
          if (row < M) {
            float v = acc[m][n][j] + bv;
            if (OBF) ((u16*)Cout)[(size_t)row * Nt + col] = f2b(v);
            else     ((float*)Cout)[(size_t)row * Nt + col] = v;
          }
        }
      }
    }
  }
  if (FUSE) {
    float ps[4][4], pd[4][4];
    #pragma unroll
    for (int m = 0; m < 4; ++m)
      #pragma unroll
      for (int j = 0; j < 4; ++j) { ps[m][j] = 0.f; pd[m][j] = 0.f; }
    #pragma unroll
    for (int n = 0; n < 4; ++n) {
      int cl = wc + n * 16 + l15;
      float wsv = attS[bn + cl], wdv = attD[bn + cl];
      #pragma unroll
      for (int m = 0; m < 4; ++m)
        #pragma unroll
        for (int j = 0; j < 4; ++j) {
          float av = acc[m][n][j];
          if (FUSE == 2) av = leakyf(tanhf(av));
          ps[m][j] = fmaf(av, wsv, ps[m][j]);
          pd[m][j] = fmaf(av, wdv, pd[m][j]);
        }
    }
    #pragma unroll
    for (int m = 0; m < 4; ++m)
      #pragma unroll
      for (int j = 0; j < 4; ++j)
        #pragma unroll
        for (int msk = 8; msk >= 1; msk >>= 1) {
          ps[m][j] += __shfl_xor(ps[m][j], msk);
          pd[m][j] += __shfl_xor(pd[m][j], msk);
        }
    if (l15 == 0) {
      #pragma unroll
      for (int m = 0; m < 4; ++m)
        #pragma unroll
        for (int j = 0; j < 4; ++j) {
          atomicAdd(&s_as[wr + m * 16 + g * 4 + j], ps[m][j]);
          atomicAdd(&s_ad[wr + m * 16 + g * 4 + j], pd[m][j]);
        }
    }
    __syncthreads();
    if (tid < 128) {
      int row = bm + tid;
      if (row < M) {
        if (FUSE == 1) {
          int h = bn >> 7;
          asrc[(size_t)row * 4 + h] = s_as[tid];
          adst[(size_t)row * 4 + h] = s_ad[tid];
        } else {
          float l0 = s_as[tid] + bias[0];
          float l1 = s_ad[tid] + bias[1];
          float mx = fmaxf(l0, l1);
          float lse = mx + logf(expf(l0 - mx) + expf(l1 - mx));
          asrc[(size_t)row * 2 + 0] = l0 - lse;
          asrc[(size_t)row * 2 + 1] = l1 - lse;
        }
      }
    }
  }
}

// ---------------------------------------------------------------------------
// Merged weight converts: wgat transpose (512 blocks) + 4 small weights (72)
// ---------------------------------------------------------------------------
__global__ void convert_all(const float* __restrict__ w_gat,
                            const float* __restrict__ w_ih, const float* __restrict__ w_hh,
                            const float* __restrict__ w_in, const float* __restrict__ w_out,
                            u16* __restrict__ wgatT,
                            u16* __restrict__ wihb, u16* __restrict__ whhb,
                            u16* __restrict__ winb, u16* __restrict__ woutb)
{
  int b = blockIdx.x;
  if (b < 512) {
    int idx = b * 256 + threadIdx.x;       // KC*F_INC = 131072
    int n = idx >> 8, k = idx & 255;
    wgatT[(size_t)n * F_INC + k] = f2b(w_gat[(size_t)k * KC + n]);
    return;
  }
  int i = (b - 512) * 256 + threadIdx.x;   // 18432 threads
  const float* src; u16* dst; int base;
  if      (i < 6144)  { src = w_ih;  dst = wihb;  base = i; }
  else if (i < 12288) { src = w_hh;  dst = whhb;  base = i - 6144; }
  else if (i < 14336) { src = w_in;  dst = winb;  base = i - 12288; }
  else                { src = w_out; dst = woutb; base = i - 14336; }
  int o = base * 8;
  float4 v0 = *(const float4*)(src + o);
  float4 v1 = *(const float4*)(src + o + 4);
  bf16x8 ov;
  ov[0] = (short)f2b(v0.x); ov[1] = (short)f2b(v0.y);
  ov[2] = (short)f2b(v0.z); ov[3] = (short)f2b(v0.w);
  ov[4] = (short)f2b(v1.x); ov[5] = (short)f2b(v1.y);
  ov[6] = (short)f2b(v1.z); ov[7] = (short)f2b(v1.w);
  *(bf16x8*)(dst + o) = ov;
}

// ---------------------------------------------------------------------------
// Batched edge counting-sort (all T at once). offs = FLAT global scan of
// (counts+1) over all T*N nodes; per-t bases (t*SEG) emerge automatically.
// ---------------------------------------------------------------------------
__global__ void count_kernel(const int* __restrict__ graph, int* __restrict__ counts) {
  int e = blockIdx.x * 256 + threadIdx.x;
  int t = blockIdx.y;
  if (e < N_EDGES) {
    int d = graph[(size_t)t * 2 * N_EDGES + N_EDGES + e];
    atomicAdd(&counts[t * N_NODES + d], 1);
  }
}

__global__ __launch_bounds__(1024) void scanA(
    const int* __restrict__ counts, int* __restrict__ offs, int* __restrict__ bsums)
{
  const int tid = threadIdx.x, lane = tid & 63, w = tid >> 6;
  __shared__ int s_wt[16];
  int i = blockIdx.x * 1024 + tid;
  int v = (i < TN) ? (counts[i] + 1) : 0;   // +1 self loop
  int x = v;
  #pragma unroll
  for (int d = 1; d < 64; d <<= 1) {
    int nvl = __shfl_up(x, d, 64);
    if (lane >= d) x += nvl;
  }
  if (lane == 63) s_wt[w] = x;
  __syncthreads();
  if (tid < 16) {
    int y = s_wt[tid];
    #pragma unroll
    for (int d = 1; d < 16; d <<= 1) {
      int nvl = __shfl_up(y, d, 64);
      if (tid >= d) y += nvl;
    }
    s_wt[tid] = y;
  }
  __syncthreads();
  int wbase = (w > 0) ? s_wt[w - 1] : 0;
  if (i < TN) offs[i] = wbase + x - v;       // block-local exclusive
  if (tid == 1023) bsums[blockIdx.x] = s_wt[15];
}

__global__ void scanB(int* __restrict__ bsums, int* __restrict__ offs) {
  const int lane = threadIdx.x;  // 64 threads, 1 block
  int carry = 0;
  for (int base = 0; base < 192; base += 64) {
    int idx = base + lane;
    int v = (idx < SCAN_BLKS) ? bsums[idx] : 0;
    int x = v;
    #pragma unroll
    for (int d = 1; d < 64; d <<= 1) {
      int nvl = __shfl_up(x, d, 64);
      if (lane >= d) x += nvl;
    }
    if (idx < SCAN_BLKS) bsums[idx] = carry + x - v;   // exclusive
    carry += __shfl(x, 63);
  }
  if (lane == 0) offs[TN] = carry;   // == T_STEPS * SEG
}

__global__ __launch_bounds__(1024) void scanC(int* __restrict__ offs, const int* __restrict__ bsums) {
  int i = blockIdx.x * 1024 + threadIdx.x;
  if (i < TN) offs[i] += bsums[blockIdx.x];
}

__global__ void scatter_kernel(const int* __restrict__ graph, const int* __restrict__ offs,
                               int* __restrict__ cursor, int* __restrict__ ssrc)
{
  int i = blockIdx.x * 256 + threadIdx.x;
  int t = blockIdx.y;
  if (i >= SEG) return;
  int s, d;
  if (i < N_EDGES) {
    s = graph[(size_t)t * 2 * N_EDGES + i];
    d = graph[(size_t)t * 2 * N_EDGES + N_EDGES + i];
  } else {
    s = d = i - N_EDGES;
  }
  int pos = offs[t * N_NODES + d] + atomicAdd(&cursor[t * N_NODES + d], 1);
  ssrc[pos] = s;
}

// ---------------------------------------------------------------------------
// Batched aggregate: head-interleaved online softmax + branch-free padded
// 8-wide gather (proven structure).
// ---------------------------------------------------------------------------
__global__ __launch_bounds__(256) void aggregate_kernel(
    const u16* __restrict__ xw, const float* __restrict__ a_src,
    const float* __restrict__ a_dst, const float* __restrict__ b_gat,
    const int* __restrict__ offs, const int* __restrict__ ssrc,
    u16* __restrict__ yout)
{
  const int wv = threadIdx.x >> 6, lane = threadIdx.x & 63;
  const int nd = blockIdx.x * 4 + wv;
  const int t  = blockIdx.y;
  const int ob = t * N_NODES + nd;
  const int beg = offs[ob], end = offs[ob + 1];
  const size_t rowbase = (size_t)t * N_NODES;
  const int he   = lane & 3;
  const int eidx = lane >> 2;
  const int hl   = lane >> 4;
  const float advh = a_dst[(rowbase + nd) * 4 + he];

  float m = -INFINITY, ssum = 0.f;
  f32x2 acc2[4];
  #pragma unroll
  for (int j = 0; j < 4; ++j) { acc2[j][0] = 0.f; acc2[j][1] = 0.f; }

#define FMA8(W, X)                                                        \
    { f32x2 _w2; _w2[0] = (W); _w2[1] = _w2[0];                           \
      f32x2 _v;                                                           \
      _v[0] = __uint_as_float((unsigned)(X).x << 16);                     \
      _v[1] = __uint_as_float((unsigned)(X).x & 0xffff0000u);             \
      acc2[0] += _w2 * _v;                                                \
      _v[0] = __uint_as_float((unsigned)(X).y << 16);                     \
      _v[1] = __uint_as_float((unsigned)(X).y & 0xffff0000u);             \
      acc2[1] += _w2 * _v;                                                \
      _v[0] = __uint_as_float((unsigned)(X).z << 16);                     \
      _v[1] = __uint_as_float((unsigned)(X).z & 0xffff0000u);             \
      acc2[2] += _w2 * _v;                                                \
      _v[0] = __uint_as_float((unsigned)(X).w << 16);                     \
      _v[1] = __uint_as_float((unsigned)(X).w & 0xffff0000u);             \
      acc2[3] += _w2 * _v; }
#define LDE(SVAR) (*(const int4*)&xw[(rowbase + (SVAR)) * KC + lane * 8])

  for (int base = beg; base < end; base += 16) {
    const int cnt = min(16, end - base);
    const int e = base + eidx;
    const int sidx = (e < end) ? ssrc[e] : ssrc[base];
    const float av = a_src[(rowbase + sidx) * 4 + he];
    const float a = (eidx < cnt) ? leakyf(av + advh) : -INFINITY;
    float cm = a;
    cm = fmaxf(cm, __shfl_xor(cm, 4));
    cm = fmaxf(cm, __shfl_xor(cm, 8));
    cm = fmaxf(cm, __shfl_xor(cm, 16));
    cm = fmaxf(cm, __shfl_xor(cm, 32));
    const float nm = fmaxf(m, cm);
    const float sc = expf(m - nm);
    const float w = expf(a - nm);
    float ts = w;
    ts += __shfl_xor(ts, 4);
    ts += __shfl_xor(ts, 8);
    ts += __shfl_xor(ts, 16);
    ts += __shfl_xor(ts, 32);
    ssum = ssum * sc + ts;
    m = nm;
    {
      const float schl = __shfl(sc, hl);
      f32x2 sc2; sc2[0] = schl; sc2[1] = schl;
      #pragma unroll
      for (int j = 0; j < 4; ++j) acc2[j] *= sc2;
    }

    const int cpad = (cnt + 3) & ~3;
    int b4 = 0;
    for (; b4 + 8 <= cpad; b4 += 8) {
      const int s0 = __shfl(sidx, (b4 + 0) << 2);
      const int s1 = __shfl(sidx, (b4 + 1) << 2);
      const int s2 = __shfl(sidx, (b4 + 2) << 2);
      const int s3 = __shfl(sidx, (b4 + 3) << 2);
      const int s4 = __shfl(sidx, (b4 + 4) << 2);
      const int s5 = __shfl(sidx, (b4 + 5) << 2);
      const int s6 = __shfl(sidx, (b4 + 6) << 2);
      const int s7 = __shfl(sidx, (b4 + 7) << 2);
      const int4 x0 = LDE(s0); const int4 x1 = LDE(s1);
      const int4 x2 = LDE(s2); const int4 x3 = LDE(s3);
      const int4 x4 = LDE(s4); const int4 x5 = LDE(s5);
      const int4 x6 = LDE(s6); const int4 x7 = LDE(s7);
      const float w0 = __shfl(w, ((b4 + 0) << 2) + hl);
      const float w1 = __shfl(w, ((b4 + 1) << 2) + hl);
      const float w2 = __shfl(w, ((b4 + 2) << 2) + hl);
      const float w3 = __shfl(w, ((b4 + 3) << 2) + hl);
      const float w4 = __shfl(w, ((b4 + 4) << 2) + hl);
      const float w5 = __shfl(w, ((b4 + 5) << 2) + hl);
      const float w6 = __shfl(w, ((b4 + 6) << 2) + hl);
      const float w7 = __shfl(w, ((b4 + 7) << 2) + hl);
      FMA8(w0, x0); FMA8(w1, x1); FMA8(w2, x2); FMA8(w3, x3);
      FMA8(w4, x4); FMA8(w5, x5); FMA8(w6, x6); FMA8(w7, x7);
    }
    if (b4 < cpad) {
      const int s0 = __shfl(sidx, (b4 + 0) << 2);
      const int s1 = __shfl(sidx, (b4 + 1) << 2);
      const int s2 = __shfl(sidx, (b4 + 2) << 2);
      const int s3 = __shfl(sidx, (b4 + 3) << 2);
      const int4 x0 = LDE(s0); const int4 x1 = LDE(s1);
      const int4 x2 = LDE(s2); const int4 x3 = LDE(s3);
      const float w0 = __shfl(w, ((b4 + 0) << 2) + hl);
      const float w1 = __shfl(w, ((b4 + 1) << 2) + hl);
      const float w2 = __shfl(w, ((b4 + 2) << 2) + hl);
      const float w3 = __shfl(w, ((b4 + 3) << 2) + hl);
      FMA8(w0, x0); FMA8(w1, x1); FMA8(w2, x2); FMA8(w3, x3);
    }
  }
#undef LDE
#undef FMA8

  const float sh = __shfl(ssum, hl);
  const float inv = 1.f / (sh + 1e-16f);
  float acc[8];
  #pragma unroll
  for (int k = 0; k < 8; ++k) {
    acc[k] = acc2[k >> 1][k & 1] * inv;
    acc[k] += __shfl_xor(acc[k], 16);
    acc[k] += __shfl_xor(acc[k], 32);
  }
  if (lane < 16) {
    bf16x8 ov;
    #pragma unroll
    for (int k = 0; k < 8; ++k) {
      float v = acc[k] * 0.25f + b_gat[lane * 8 + k];
      ov[k] = (short)f2b(leakyf(v));
    }
    *(bf16x8*)&yout[(rowbase + nd) * GHD + lane * 8] = ov;
  }
}

// ---------------------------------------------------------------------------
// Fused GRU recurrence + q-projection. 625 blocks x 32 rows. gh-GEMM per
// step; h fp32 in regs + bf16 in swizzled LDS hA; W_hh per-kt via
// global_load_lds; gh restaged through LDS. After t=7: q = h @ W_in^T.
// ---------------------------------------------------------------------------
__global__ __launch_bounds__(256) void gru_seq(
    const u16* __restrict__ Whh, const u16* __restrict__ Win,
    const float* __restrict__ b_hh, const u16* __restrict__ giall,
    u16* __restrict__ ctx, u16* __restrict__ qb)
{
  __shared__ u16 hA[32][128];       // 8 KB: h bf16, slot^=(row&7) swizzle
  __shared__ u16 reg2[12288];       // 24 KB: Bs (384x32) during MFMA, gh after
  u16 (*Bs)[32] = (u16(*)[32])reg2;
  const int tid = threadIdx.x, lane = tid & 63, wv = tid >> 6;
  const int l15 = lane & 15, g = lane >> 4;
  const int bm = blockIdx.x * 32;   // 20000 = 625*32, no tail

  const int sr = tid >> 2, sd = tid & 3;
  const int ssb = sd ^ ((sr >> 1) & 3);
  const u16* bS[6]; u16* lB[6];
  #pragma unroll
  for (int p = 0; p < 6; ++p) {
    bS[p] = Whh + (size_t)(sr + p * 64) * GHD + ssb * 8;
    lB[p] = reg2 + (size_t)(p * 256 + (tid & ~63)) * 8;
  }
  float bbv[6];
  #pragma unroll
  for (int n = 0; n < 6; ++n) bbv[n] = b_hh[wv * 96 + n * 16 + l15];

  const int cr = tid >> 3;
  const int cg = (tid & 7) * 8;
  const int grow = bm + cr;
  const size_t gb = (size_t)grow * G3;
  const size_t cb = (size_t)grow * GHD;
  float hp[2][8];

  // ---- t = 0: h = (1-z)*tanh(i_n + r*b_hh_n), gh == b_hh ----
  #pragma unroll
  for (int q = 0; q < 2; ++q) {
    const int c0 = cg + q * 64;
    bf16x8 ir8 = *(const bf16x8*)&giall[gb + c0];
    bf16x8 iz8 = *(const bf16x8*)&giall[gb + 128 + c0];
    bf16x8 in8 = *(const bf16x8*)&giall[gb + 256 + c0];
    float4 br0 = *(const float4*)&b_hh[c0];       float4 br1 = *(const float4*)&b_hh[c0 + 4];
    float4 bz0 = *(const float4*)&b_hh[128 + c0]; float4 bz1 = *(const float4*)&b_hh[128 + c0 + 4];
    float4 bn0 = *(const float4*)&b_hh[256 + c0]; float4 bn1 = *(const float4*)&b_hh[256 + c0 + 4];
    float bhr[8] = {br0.x, br0.y, br0.z, br0.w, br1.x, br1.y, br1.z, br1.w};
    float bhz[8] = {bz0.x, bz0.y, bz0.z, bz0.w, bz1.x, bz1.y, bz1.z, bz1.w};
    float bhn[8] = {bn0.x, bn0.y, bn0.z, bn0.w, bn1.x, bn1.y, bn1.z, bn1.w};
    bf16x8 hv;
    #pragma unroll
    for (int k = 0; k < 8; ++k) {
      float rr = sigf(b2f((u16)ir8[k]) + bhr[k]);
      float zz = sigf(b2f((u16)iz8[k]) + bhz[k]);
      float nn = tanhf(b2f((u16)in8[k]) + rr * bhn[k]);
      float h = (1.f - zz) * nn;
      hp[q][k] = h;
      hv[k] = (short)f2b(h);
    }
    const int sl = (c0 >> 3) ^ (cr & 7);
    *(bf16x8*)&hA[cr][sl * 8] = hv;
    *(bf16x8*)&ctx[cb + c0] = hv;
  }
  __syncthreads();

  // ---- t = 1..7 ----
  for (int t = 1; t < T_STEPS; ++t) {
    const u16* gi_t = giall + (size_t)t * N_NODES * G3;
    u16* ctx_t = ctx + (size_t)t * N_NODES * GHD;
    f32x4 acc[2][6];
    #pragma unroll
    for (int m = 0; m < 2; ++m)
      #pragma unroll
      for (int n = 0; n < 6; ++n)
        #pragma unroll
        for (int j = 0; j < 4; ++j) acc[m][n][j] = 0.f;

    #pragma unroll
    for (int kt = 0; kt < 4; ++kt) {
      const int ko = kt * 32;
      #pragma unroll
      for (int p = 0; p < 6; ++p) gload16(bS[p] + ko, lB[p]);
      __syncthreads();
      bf16x8 af[2], bfr[6];
      #pragma unroll
      for (int m = 0; m < 2; ++m) {
        int row = m * 16 + l15;
        int sl = (kt * 4 + g) ^ (row & 7);
        af[m] = *(const bf16x8*)&hA[row][sl * 8];
      }
      #pragma unroll
      for (int n = 0; n < 6; ++n) {
        int rowb = wv * 96 + n * 16 + l15;
        bfr[n] = *(const bf16x8*)&Bs[rowb][(g ^ ((rowb >> 1) & 3)) * 8];
      }
      #pragma unroll
      for (int m = 0; m < 2; ++m)
        #pragma unroll
        for (int n = 0; n < 6; ++n)
          acc[m][n] = __builtin_amdgcn_mfma_f32_16x16x32_bf16(af[m], bfr[n], acc[m][n], 0, 0, 0);
      __syncthreads();
    }
    // stage gh (+b_hh) into reg2 (clobbers Bs; all reads done)
    #pragma unroll
    for (int m = 0; m < 2; ++m)
      #pragma unroll
      for (int n = 0; n < 6; ++n) {
        int c = wv * 96 + n * 16 + l15;
        #pragma unroll
        for (int j = 0; j < 4; ++j) {
          int r = m * 16 + g * 4 + j;
          reg2[r * 384 + (((c >> 3) ^ (r & 7)) << 3) + (c & 7)] = f2b(acc[m][n][j] + bbv[n]);
        }
      }
    __syncthreads();
    // combine (reads reg2, writes hA + ctx; hp carries fp32 state)
    #pragma unroll
    for (int q = 0; q < 2; ++q) {
      const int c0 = cg + q * 64;
      const int sl0 = ((c0 >> 3) ^ (cr & 7));
      const int sl1 = (((128 + c0) >> 3) ^ (cr & 7));
      const int sl2 = (((256 + c0) >> 3) ^ (cr & 7));
      bf16x8 hr8 = *(bf16x8*)&reg2[cr * 384 + sl0 * 8];
      bf16x8 hz8 = *(bf16x8*)&reg2[cr * 384 + sl1 * 8];
      bf16x8 hn8 = *(bf16x8*)&reg2[cr * 384 + sl2 * 8];
      bf16x8 ir8 = *(const bf16x8*)&gi_t[gb + c0];
      bf16x8 iz8 = *(const bf16x8*)&gi_t[gb + 128 + c0];
      bf16x8 in8 = *(const bf16x8*)&gi_t[gb + 256 + c0];
      bf16x8 hv;
      #pragma unroll
      for (int k = 0; k < 8; ++k) {
        float rr = sigf(b2f((u16)ir8[k]) + b2f((u16)hr8[k]));
        float zz = sigf(b2f((u16)iz8[k]) + b2f((u16)hz8[k]));
        float nn = tanhf(b2f((u16)in8[k]) + rr * b2f((u16)hn8[k]));
        float h = (1.f - zz) * nn + zz * hp[q][k];
        hp[q][k] = h;
        hv[k] = (short)f2b(h);
      }
      const int slh = (c0 >> 3) ^ (cr & 7);
      *(bf16x8*)&hA[cr][slh * 8] = hv;
      *(bf16x8*)&ctx_t[cb + c0] = hv;
    }
    __syncthreads();
  }

  // ---- q = h_final @ W_in^T (32x128 @ (128,128)^T), same machinery ----
  {
    const u16* qS[2]; u16* lQ[2];
    #pragma unroll
    for (int p = 0; p < 2; ++p) {
      qS[p] = Win + (size_t)(sr + p * 64) * GHD + ssb * 8;
      lQ[p] = reg2 + (size_t)(p * 256 + (tid & ~63)) * 8;
    }
    f32x4 accq[2][2];
    #pragma unroll
    for (int m = 0; m < 2; ++m)
      #pragma unroll
      for (int n = 0; n < 2; ++n)
        #pragma unroll
        for (int j = 0; j < 4; ++j) accq[m][n][j] = 0.f;

    #pragma unroll
    for (int kt = 0; kt < 4; ++kt) {
      const int ko = kt * 32;
      #pragma unroll
      for (int p = 0; p < 2; ++p) gload16(qS[p] + ko, lQ[p]);
      __syncthreads();
      bf16x8 af[2], bq[2];
      #pragma unroll
      for (int m = 0; m < 2; ++m) {
        int row = m * 16 + l15;
        int sl = (kt * 4 + g) ^ (row & 7);
        af[m] = *(const bf16x8*)&hA[row][sl * 8];
      }
      #pragma unroll
      for (int n = 0; n < 2; ++n) {
        int rowb = wv * 32 + n * 16 + l15;     // 0..127
        bq[n] = *(const bf16x8*)&Bs[rowb][(g ^ ((rowb >> 1) & 3)) * 8];
      }
      #pragma unroll
      for (int m = 0; m < 2; ++m)
        #pragma unroll
        for (int n = 0; n < 2; ++n)
          accq[m][n] = __builtin_amdgcn_mfma_f32_16x16x32_bf16(af[m], bq[n], accq[m][n], 0, 0, 0);
      __syncthreads();
    }
    #pragma unroll
    for (int m = 0; m < 2; ++m) {
      int row0 = bm + m * 16 + g * 4;
      #pragma unroll
      for (int n = 0; n < 2; ++n) {
        int col = wv * 32 + n * 16 + l15;
        #pragma unroll
        for (int j = 0; j < 4; ++j)
          qb[(size_t)(row0 + j) * GHD + col] = f2b(accq[m][n][j]);
      }
    }
  }
}

// ---------------------------------------------------------------------------
// Temporal attention middle: scores + softmax + mix. One wave / node.
// ---------------------------------------------------------------------------
__global__ __launch_bounds__(256) void attn_mid(
    const u16* __restrict__ ctx, const u16* __restrict__ qb,
    u16* __restrict__ comb)
{
  const int node = blockIdx.x * 4 + (threadIdx.x >> 6);
  const int lane = threadIdx.x & 63;
  if (node >= N_NODES) return;
  const float q0 = b2f(qb[(size_t)node * GHD + lane]);
  const float q1 = b2f(qb[(size_t)node * GHD + 64 + lane]);
  float c0[T_STEPS], c1[T_STEPS], w[T_STEPS];
  float mx = -1e30f;
  #pragma unroll
  for (int t = 0; t < T_STEPS; ++t) {
    const u16* cr = ctx + ((size_t)t * N_NODES + node) * GHD;
    c0[t] = b2f(cr[lane]); c1[t] = b2f(cr[64 + lane]);
    float p = q0 * c0[t] + q1 * c1[t];
    #pragma unroll
    for (int m = 32; m >= 1; m >>= 1) p += __shfl_xor(p, m);
    w[t] = p;
    mx = fmaxf(mx, p);
  }
  float s = 0.f;
  #pragma unroll
  for (int t = 0; t < T_STEPS; ++t) { w[t] = expf(w[t] - mx); s += w[t]; }
  const float inv = 1.f / s;
  float m0 = 0.f, m1 = 0.f;
  #pragma unroll
  for (int t = 0; t < T_STEPS; ++t) { m0 = fmaf(w[t], c0[t], m0); m1 = fmaf(w[t], c1[t], m1); }
  m0 *= inv; m1 *= inv;
  u16* cb = comb + (size_t)node * 2 * GHD;
  cb[lane]       = f2b(m0);
  cb[64 + lane]  = f2b(m1);
  cb[128 + lane] = qb[(size_t)node * GHD + lane];
  cb[192 + lane] = qb[(size_t)node * GHD + 64 + lane];
}

// ---------------------------------------------------------------------------
extern "C" void kernel_launch(void* const* d_in, const int* in_sizes, int n_in,
                              void* d_out, int out_size, void* d_ws, size_t ws_size,
                              hipStream_t stream)
{
  const int*   graph     = (const int*)  d_in[0];
  const float* fts       = (const float*)d_in[1];
  const float* W_gat     = (const float*)d_in[3];
  const float* att_src   = (const float*)d_in[4];
  const float* att_dst   = (const float*)d_in[5];
  const float* b_gat     = (const float*)d_in[6];
  const float* W_ih      = (const float*)d_in[7];
  const float* W_hh      = (const float*)d_in[8];
  const float* b_ih      = (const float*)d_in[9];
  const float* b_hh      = (const float*)d_in[10];
  const float* W_att_in  = (const float*)d_in[11];
  const float* W_att_out = (const float*)d_in[12];
  const float* W_cls     = (const float*)d_in[13];
  const float* b_cls     = (const float*)d_in[14];
  float* out = (float*)d_out;

  char* ws = (char*)d_ws;
  size_t off = 0;
  auto alloc = [&](size_t bytes) {
    void* p = ws + off;
    off = (off + bytes + 255) & ~(size_t)255;
    return p;
  };
  const size_t NT = (size_t)TN;                    // 160000 rows
  u16*   wgatT = (u16*)alloc((size_t)KC * F_INC * 2);
  u16*   wihb  = (u16*)alloc((size_t)G3 * GHD * 2);
  u16*   whhb  = (u16*)alloc((size_t)G3 * GHD * 2);
  u16*   winb  = (u16*)alloc((size_t)GHD * GHD * 2);
  u16*   woutb = (u16*)alloc((size_t)GHD * 2 * GHD * 2);
  u16*   xw    = (u16*)alloc(NT * KC * 2);          // 164 MB
  float* asrc  = (float*)alloc(NT * 4 * 4);
  float* adst  = (float*)alloc(NT * 4 * 4);
  u16*   yall  = (u16*)alloc(NT * GHD * 2);         // 41 MB
  u16*   giall = (u16*)alloc(NT * G3 * 2);          // 123 MB
  u16*   ctx   = (u16*)alloc(NT * GHD * 2);         // 41 MB
  u16*   qb    = (u16*)alloc((size_t)N_NODES * GHD * 2);
  u16*   comb  = (u16*)alloc((size_t)N_NODES * 2 * GHD * 2);
  int* counts  = (int*)alloc((size_t)2 * TN * 4);   // counts + cursor
  int* cursor  = counts + TN;
  int* offs    = (int*)alloc((size_t)(TN + 1) * 4);
  int* bsums   = (int*)alloc((size_t)256 * 4);
  int* ssrc    = (int*)alloc((size_t)T_STEPS * SEG * 4);

  // merged weight converts (wgat transpose + 4 small weights)
  convert_all<<<dim3(584), 256, 0, stream>>>(W_gat, W_ih, W_hh, W_att_in, W_att_out,
                                             wgatT, wihb, whhb, winb, woutb);

  // batched edge sort (flat 3-phase scan)
  hipMemsetAsync(counts, 0, (size_t)2 * TN * 4, stream);
  count_kernel<<<dim3(N_EDGES / 256, T_STEPS), 256, 0, stream>>>(graph, counts);
  scanA<<<dim3(SCAN_BLKS), 1024, 0, stream>>>(counts, offs, bsums);
  scanB<<<dim3(1), 64, 0, stream>>>(bsums, offs);
  scanC<<<dim3(SCAN_BLKS), 1024, 0, stream>>>(offs, bsums);
  scatter_kernel<<<dim3((SEG + 255) / 256, T_STEPS), 256, 0, stream>>>(graph, offs, cursor, ssrc);

  // xw = fts(fp32) @ W_gat^T for ALL t (reg-staged convert) + fused a_src/a_dst
  gemm_bf16<1, 1, 1><<<dim3(KC / 128, (int)(NT / 128)), 256, 0, stream>>>(
      fts, wgatT, nullptr, xw, (int)NT, F_INC, KC, 1, att_src, att_dst, asrc, adst);

  // batched aggregate -> y for ALL t
  aggregate_kernel<<<dim3(N_NODES / 4, T_STEPS), 256, 0, stream>>>(
      xw, asrc, adst, b_gat, offs, ssrc, yall);

  // gi = y @ W_ih^T + b_ih for ALL t (fat parallel GEMM)
  gemm_bf16<1, 0, 0><<<dim3(G3 / 128, (int)(NT / 128)), 256, 0, stream>>>(
      yall, wihb, b_ih, giall, (int)NT, GHD, G3, 1, nullptr, nullptr, nullptr, nullptr);

  // GRU recurrence + fused q-projection (one kernel, 32 KB LDS)
  gru_seq<<<dim3(N_NODES / 32), 256, 0, stream>>>(whhb, winb, b_hh, giall, ctx, qb);

  // temporal attention tail
  attn_mid<<<dim3(N_NODES / 4), 256, 0, stream>>>(ctx, qb, comb);
  // out-GEMM with fused classifier + log_softmax (writes d_out directly)
  gemm_bf16<0, 2, 0><<<dim3(1, (N_NODES + 127) / 128), 256, 0, stream>>>(
      comb, woutb, b_cls, nullptr, N_NODES, 2 * GHD, GHD, 0,
      W_cls, W_cls + GHD, out, nullptr);
}